// Round 1
// 959.680 us; speedup vs baseline: 1.3264x; 1.3264x over previous
//
#include <hip/hip_runtime.h>
#include <stdint.h>

typedef unsigned short u16;
typedef unsigned int u32;
typedef short bf16x8 __attribute__((ext_vector_type(8)));
typedef float f32x4 __attribute__((ext_vector_type(4)));
typedef u16 u16x4 __attribute__((ext_vector_type(4)));

#define DEV __device__ __forceinline__

DEV float bf2f(u16 u) { union { float f; u32 i; } x; x.i = ((u32)u) << 16; return x.f; }
DEV u16 f2bf(float f) {
  union { float f; u32 i; } x; x.f = f;
  u32 i = x.i;
  u32 r = (i + 0x7fffu + ((i >> 16) & 1u)) >> 16;  // RTNE
  return (u16)r;
}

// async global->LDS, 16B per lane. lds base must be wave-uniform; HW adds lane*16.
DEV void gl_lds16(const u16* g, u16* l) {
  __builtin_amdgcn_global_load_lds((const __attribute__((address_space(1))) u32*)g,
                                   (__attribute__((address_space(3))) u32*)l, 16, 0, 0);
}

// ---------------- cast fp32 -> bf16 (vectorized) ----------------
__global__ __launch_bounds__(256) void cast_f32_bf16(const float* __restrict__ in,
                                                     u16* __restrict__ out, int n4) {
  int i = blockIdx.x * 256 + threadIdx.x;
  if (i >= n4) return;
  float4 v = ((const float4*)in)[i];
  u16x4 o;
  o.x = f2bf(v.x); o.y = f2bf(v.y); o.z = f2bf(v.z); o.w = f2bf(v.w);
  ((u16x4*)out)[i] = o;
}

// ---------------- transpose + cast: W (K,N) fp32 -> Wt (N,K) bf16 ----------------
__global__ __launch_bounds__(256) void transpose_cast(const float* __restrict__ W,
                                                      u16* __restrict__ Wt, int K, int N) {
  __shared__ float tile[64][65];
  int n0 = blockIdx.x * 64;
  int k0 = blockIdx.y * 64;
#pragma unroll
  for (int i = 0; i < 16; ++i) {
    int idx = threadIdx.x + i * 256;
    int r = idx >> 6, c = idx & 63;             // r: k-off, c: n-off
    tile[r][c] = W[(size_t)(k0 + r) * N + n0 + c];
  }
  __syncthreads();
#pragma unroll
  for (int i = 0; i < 16; ++i) {
    int idx = threadIdx.x + i * 256;
    int r = idx >> 6, c = idx & 63;             // r: n-off, c: k-off
    Wt[(size_t)(n0 + r) * K + k0 + c] = f2bf(tile[c][r]);
  }
}

// ---------------- transpose V: rows of kcv (B*L, 4096), v = cols 2048+h*128+dv -> Vt (B,H,128,L) ----------------
__global__ __launch_bounds__(256) void transpose_v(const u16* __restrict__ KCV,
                                                   u16* __restrict__ Vt) {
  __shared__ float tile[64][65];
  int l0 = blockIdx.x * 64;   // 32 tiles over L
  int d0 = blockIdx.y * 64;   // 2 tiles over 128
  int bh = blockIdx.z;        // b*16+h
  int b = bh >> 4, h = bh & 15;
#pragma unroll
  for (int i = 0; i < 16; ++i) {
    int idx = threadIdx.x + i * 256;
    int r = idx >> 6, c = idx & 63;
    tile[r][c] = bf2f(KCV[(size_t)(b * 2048 + l0 + r) * 4096 + 2048 + h * 128 + d0 + c]);
  }
  __syncthreads();
#pragma unroll
  for (int i = 0; i < 16; ++i) {
    int idx = threadIdx.x + i * 256;
    int rr = idx >> 6, cc = idx & 63;  // rr: dv-off, cc: l-off
    Vt[((size_t)bh * 128 + d0 + rr) * 2048 + l0 + cc] = f2bf(tile[cc][rr]);
  }
}

// ---------------- GEMM: C(MxN) = A(MxK bf16, row-stride lda) * Bt(NxK bf16)^T ----------------
DEV void ep_set(u16* E, int i, float v) { E[i] = f2bf(v); }
DEV void ep_set(float* E, int i, float v) { E[i] = v; }

template <typename OT>
__global__ __launch_bounds__(256) void gemm_bt(const u16* __restrict__ A, int lda,
                                               const u16* __restrict__ Bt,
                                               OT* __restrict__ C, int ldc,
                                               int M, int N, int K) {
  __shared__ u16 smem_ab[2 * 128 * 32];   // As | Bs (contiguous 16KB; reused by epilogue)
  u16* As = smem_ab;
  u16* Bs = smem_ab + 128 * 32;
  const int tid = threadIdx.x;
  const int lane = tid & 63;
  const int w = tid >> 6;       // 0..3
  const int quad = lane >> 4;   // 0..3
  const int l15 = lane & 15;
  const int m0 = blockIdx.y * 128;
  const int n0 = blockIdx.x * 128;
  const int wm = (w & 1) * 64;
  const int wn = (w >> 1) * 64;

  f32x4 acc[4][4] = {};

  for (int k0 = 0; k0 < K; k0 += 32) {
#pragma unroll
    for (int it = 0; it < 2; ++it) {
      int ca = w * 128 + it * 64;       // wave-uniform base chunk
      int c = ca + lane;
      int row = c >> 2, kc = (c & 3) * 8;
      gl_lds16(A + (size_t)(m0 + row) * lda + k0 + kc, &As[ca * 8]);
      gl_lds16(Bt + (size_t)(n0 + row) * K + k0 + kc, &Bs[ca * 8]);
    }
    __syncthreads();   // waits vmcnt(0) for global_load_lds
    bf16x8 af[4], bf[4];
#pragma unroll
    for (int mt = 0; mt < 4; ++mt) af[mt] = *(const bf16x8*)&As[(wm + mt * 16 + l15) * 32 + quad * 8];
#pragma unroll
    for (int nt = 0; nt < 4; ++nt) bf[nt] = *(const bf16x8*)&Bs[(wn + nt * 16 + l15) * 32 + quad * 8];
#pragma unroll
    for (int mt = 0; mt < 4; ++mt)
#pragma unroll
      for (int nt = 0; nt < 4; ++nt)
        acc[mt][nt] = __builtin_amdgcn_mfma_f32_16x16x32_bf16(af[mt], bf[nt], acc[mt][nt], 0, 0, 0);
    __syncthreads();
  }

  // wide-store epilogue through LDS (smem_ab free after final barrier).
  // Wave-private region -> only lgkmcnt fences needed (DS ops are in-order per wave).
  OT* Ew = ((OT*)smem_ab) + w * 1024;   // 16 rows x 64 cols per wave
#pragma unroll
  for (int mt = 0; mt < 4; ++mt) {
#pragma unroll
    for (int nt = 0; nt < 4; ++nt)
#pragma unroll
      for (int r = 0; r < 4; ++r)
        ep_set(Ew, (quad * 4 + r) * 64 + nt * 16 + l15, acc[mt][nt][r]);
    asm volatile("s_waitcnt lgkmcnt(0)" ::: "memory");
#pragma unroll
    for (int it2 = 0; it2 < 4; ++it2) {
      int row_i = it2 * 4 + quad;
      int colg = n0 + wn + l15 * 4;
      if (colg < N) {   // only trims for the N=64 (W_KR) GEMM
        size_t off = (size_t)(m0 + wm + mt * 16 + row_i) * ldc + colg;
        if constexpr (sizeof(OT) == 2) {
          *(u16x4*)&C[off] = *(const u16x4*)&Ew[row_i * 64 + l15 * 4];
        } else {
          *(float4*)&C[off] = *(const float4*)&Ew[row_i * 64 + l15 * 4];
        }
      }
    }
  }
}

// ---------------- build q / k: rope + concat + L2-normalize, one wave per (token, head) ----------------
__global__ __launch_bounds__(256) void build_q(const u16* __restrict__ qcr,  // (B*L, 3072): qc|qr
                                               const float* __restrict__ s_qk,
                                               u16* __restrict__ qn) {
  const int wid = blockIdx.x * 4 + (threadIdx.x >> 6);
  const int lane = threadIdx.x & 63;
  const int token = wid >> 4;     // b*L + l
  const int h = wid & 15;
  const int b = token >> 11;
  const int l = token & 2047;
  float v0 = bf2f(qcr[(size_t)token * 3072 + h * 128 + lane]);
  float v1 = bf2f(qcr[(size_t)token * 3072 + h * 128 + 64 + lane]);
  int j = lane & 31;
  float freq = powf(10000.f, -(float)j * (1.f / 32.f));
  float ang = (float)l * freq;
  float cs = cosf(ang), sn = sinf(ang);
  float xr = bf2f(qcr[(size_t)token * 3072 + 2048 + h * 64 + lane]);
  float xo = bf2f(qcr[(size_t)token * 3072 + 2048 + h * 64 + (lane ^ 32)]);
  float v2 = (lane < 32) ? (xr * cs - xo * sn) : (xr * cs + xo * sn);
  float ss = v0 * v0 + v1 * v1 + v2 * v2;
#pragma unroll
  for (int off = 1; off < 64; off <<= 1) ss += __shfl_xor(ss, off, 64);
  float scale = s_qk[0] / fmaxf(sqrtf(ss), 1e-12f);
  u16* out = qn + (((size_t)(b * 16 + h) * 2048) + l) * 192;
  out[lane] = f2bf(v0 * scale);
  out[64 + lane] = f2bf(v1 * scale);
  out[128 + lane] = f2bf(v2 * scale);
}

__global__ __launch_bounds__(256) void build_k(const u16* __restrict__ kcv,  // (B*L, 4096): kc|v
                                               const u16* __restrict__ krr,  // (B*L, 64)
                                               u16* __restrict__ kn) {
  const int wid = blockIdx.x * 4 + (threadIdx.x >> 6);
  const int lane = threadIdx.x & 63;
  const int token = wid >> 4;
  const int h = wid & 15;
  const int b = token >> 11;
  const int l = token & 2047;
  float v0 = bf2f(kcv[(size_t)token * 4096 + h * 128 + lane]);
  float v1 = bf2f(kcv[(size_t)token * 4096 + h * 128 + 64 + lane]);
  int j = lane & 31;
  float freq = powf(10000.f, -(float)j * (1.f / 32.f));
  float ang = (float)l * freq;
  float cs = cosf(ang), sn = sinf(ang);
  float xr = bf2f(krr[(size_t)token * 64 + lane]);
  float xo = bf2f(krr[(size_t)token * 64 + (lane ^ 32)]);
  float v2 = (lane < 32) ? (xr * cs - xo * sn) : (xr * cs + xo * sn);
  float ss = v0 * v0 + v1 * v1 + v2 * v2;
#pragma unroll
  for (int off = 1; off < 64; off <<= 1) ss += __shfl_xor(ss, off, 64);
  float scale = 1.0f / fmaxf(sqrtf(ss), 1e-12f);
  u16* out = kn + (((size_t)(b * 16 + h) * 2048) + l) * 192;
  out[lane] = f2bf(v0 * scale);
  out[64 + lane] = f2bf(v1 * scale);
  out[128 + lane] = f2bf(v2 * scale);
}

// ---------------- flash attention (causal), 512 thr, 256 q-rows/block ----------------
// Static-max softmax: q,k are unit-normalized and q pre-scaled by s_qk, so every
// score <= s_qk[0] (Cauchy-Schwarz). p = exp(s - SMAX) needs NO running max, NO
// rescale pass, NO cross-lane reductions; the denominator l accumulates through an
// extra ones-operand MFMA (every output column = row sum of P).
// Each wave owns 32 q rows (two 16-row m-frags); K/V LDS reads are shared across
// both frags -> 42 MFMA per tile per wave between barriers. 32-key KV tiles,
// double-buffered LDS with prefetch-after-barrier (vmcnt drained by barrier).
// LDS 59392B, ~180 VGPR -> 1 block/CU (8 waves); halved grid halves K/V traffic.
__global__ __launch_bounds__(512, 2) void flash_attn(const u16* __restrict__ Q,   // (B,H,L,192)
                                                     const u16* __restrict__ Kn,  // (B,H,L,192)
                                                     const u16* __restrict__ Vt,  // (B,H,128,L)
                                                     const float* __restrict__ s_qk,
                                                     u16* __restrict__ O) {       // (B,L,2048)
  constexpr int L = 2048, DQK = 192, DV = 128;
  constexpr int PSTR = 36;
  __shared__ u16 smem[29696];          // Ks[2][32*192] | Vs[2][128*32] | Ps[8*32*36] = 59392 B
  u16* KsBuf = smem;                   // 2 x 6144
  u16* VsBuf = smem + 12288;           // 2 x 4096
  u16* Ps    = smem + 20480;           // 9216
  const int tid = threadIdx.x;
  const int lane = tid & 63;
  const int w = tid >> 6;       // 0..7, q-row group (32 rows each)
  const int quad = lane >> 4;
  const int l15 = lane & 15;
  // block mapping: all 8 qt of one bh on one XCD (lin%8 heuristic), long blocks
  // first within each bh-group (round-2 backfill pairs antithetically: 8+64, 16+56, ...)
  const int lin = blockIdx.x;   // 512 blocks
  const int xcd = lin & 7;
  const int g = lin >> 3;
  const int bh = ((g >> 3) << 3) | xcd;
  const int qt = 7 - (g & 7);
  const int b = bh >> 4, h = bh & 15;
  const float SMAX = s_qk[0];   // upper bound on every score

  const u16* Qg = Q + ((size_t)bh * L + qt * 256) * DQK;
  const u16* Kg = Kn + (size_t)bh * L * DQK;
  const u16* Vg = Vt + (size_t)bh * DV * L;

  // stage one 32-key K/V tile into buffer bufi.
  // K: 32 rows x 24 chunks = 768 chunks (16B), swizzled phys_c = c ^ (r&7).
  // V: 128 dv x 4 chunks = 512 chunks, linear.
  auto stage = [&](int kt2, int bufi) {
    u16* KsB = KsBuf + bufi * 6144;
    u16* VsB = VsBuf + bufi * 4096;
#pragma unroll
    for (int it = 0; it < 3; ++it) {
      int B0 = it * 512 + w * 64;            // wave-uniform
      if (B0 < 768) {
        int p = B0 + lane;
        int r = p / 24, cp = p % 24;
        int c = cp ^ (r & 7);
        gl_lds16(Kg + (size_t)(kt2 * 32 + r) * DQK + c * 8, &KsB[B0 * 8]);
      } else if (B0 < 1280) {
        int q = B0 - 768 + lane;
        int dv = q >> 2, cp = q & 3;
        gl_lds16(Vg + (size_t)dv * L + kt2 * 32 + cp * 8, &VsB[(B0 - 768) * 8]);
      }
    }
  };

  // Q fragments in registers: wave w owns q rows w*32 .. w*32+31 (two m-frags)
  bf16x8 qf[2][6];
#pragma unroll
  for (int mt = 0; mt < 2; ++mt)
#pragma unroll
    for (int kd = 0; kd < 6; ++kd)
      qf[mt][kd] = *(const bf16x8*)&Qg[(w * 32 + mt * 16 + l15) * DQK + kd * 32 + quad * 8];

  bf16x8 ones;
#pragma unroll
  for (int j = 0; j < 8; ++j) ones[j] = (short)0x3F80;   // bf16 1.0

  f32x4 oacc[2][8] = {};
  f32x4 accL[2] = {};           // running row-sum of P (ones-MFMA), no rescale needed

  const int nkv = 8 * qt + 8;   // 32-key tiles
  stage(0, 0);
  __syncthreads();

  for (int kt = 0; kt < nkv; ++kt) {
    const int cur = kt & 1;
    if (kt + 1 < nkv) stage(kt + 1, cur ^ 1);   // prefetch overlaps compute below
    const u16* KsC = KsBuf + cur * 6144;
    const u16* VsC = VsBuf + cur * 4096;

    // S (2 x 16q x 32k) per wave; K reads shared across both m-frags
    f32x4 s[2][2] = {};
#pragma unroll
    for (int kd = 0; kd < 6; ++kd) {
#pragma unroll
      for (int nt = 0; nt < 2; ++nt) {
        int row = nt * 16 + l15;
        int cp = (kd * 4 + quad) ^ (l15 & 7);
        bf16x8 bb = *(const bf16x8*)&KsC[row * DQK + cp * 8];
#pragma unroll
        for (int mt = 0; mt < 2; ++mt)
          s[mt][nt] = __builtin_amdgcn_mfma_f32_16x16x32_bf16(qf[mt][kd], bb, s[mt][nt], 0, 0, 0);
      }
    }

    // causal mask + static-max exp, P -> per-wave LDS (C-layout scatter)
    const int kcol = kt * 32 + l15;
    u16* Pw = &Ps[w * 32 * PSTR];
#pragma unroll
    for (int mt = 0; mt < 2; ++mt) {
      const int qrow_base = qt * 256 + w * 32 + mt * 16 + quad * 4;
#pragma unroll
      for (int r = 0; r < 4; ++r)
#pragma unroll
        for (int nt = 0; nt < 2; ++nt) {
          float p = (kcol + nt * 16 > qrow_base + r) ? 0.f : __expf(s[mt][nt][r] - SMAX);
          Pw[(mt * 16 + quad * 4 + r) * PSTR + nt * 16 + l15] = f2bf(p);
        }
    }
    asm volatile("s_waitcnt lgkmcnt(0)" ::: "memory");  // within-wave WAR/RAW order

    // A-layout P reads; l accumulates via ones-MFMA; V reads shared across m-frags
    bf16x8 pf[2];
#pragma unroll
    for (int mt = 0; mt < 2; ++mt) {
      pf[mt] = *(const bf16x8*)&Pw[(mt * 16 + l15) * PSTR + quad * 8];
      accL[mt] = __builtin_amdgcn_mfma_f32_16x16x32_bf16(pf[mt], ones, accL[mt], 0, 0, 0);
    }
#pragma unroll
    for (int nt2 = 0; nt2 < 8; ++nt2) {
      bf16x8 vv = *(const bf16x8*)&VsC[(nt2 * 16 + l15) * 32 + quad * 8];
#pragma unroll
      for (int mt = 0; mt < 2; ++mt)
        oacc[mt][nt2] = __builtin_amdgcn_mfma_f32_16x16x32_bf16(pf[mt], vv, oacc[mt][nt2], 0, 0, 0);
    }
    __syncthreads();  // drains prefetch (vmcnt) + frees cur buffer
  }

  // epilogue: wide O store via LDS transpose, two 16-row passes per wave.
  // smem front [0,16384) is free after the final in-loop barrier.
  float rinv[2][4];
#pragma unroll
  for (int mt = 0; mt < 2; ++mt)
#pragma unroll
    for (int r = 0; r < 4; ++r) rinv[mt][r] = 1.0f / accL[mt][r];
  u16* Ew = smem + w * 2048;    // 16 rows x 128 cols per wave (8 waves = 32KB)
#pragma unroll
  for (int mt = 0; mt < 2; ++mt) {
#pragma unroll
    for (int nt2 = 0; nt2 < 8; ++nt2)
#pragma unroll
      for (int r = 0; r < 4; ++r)
        Ew[(quad * 4 + r) * 128 + nt2 * 16 + l15] = f2bf(oacc[mt][nt2][r] * rinv[mt][r]);
    asm volatile("s_waitcnt lgkmcnt(0)" ::: "memory");
#pragma unroll
    for (int it2 = 0; it2 < 4; ++it2) {
      int row_i = it2 * 4 + quad;
      int lg = qt * 256 + w * 32 + mt * 16 + row_i;
      uint4 v = *(const uint4*)&Ew[row_i * 128 + l15 * 8];
      *(uint4*)&O[((size_t)b * L + lg) * 2048 + h * 128 + l15 * 8] = v;
    }
  }
}

// ---------------- launcher ----------------
extern "C" void kernel_launch(void* const* d_in, const int* in_sizes, int n_in,
                              void* d_out, int out_size, void* d_ws, size_t ws_size,
                              hipStream_t stream) {
  const float* x     = (const float*)d_in[0];
  const float* W_DKV = (const float*)d_in[1];
  const float* W_UK  = (const float*)d_in[2];
  const float* W_UV  = (const float*)d_in[3];
  const float* W_DQ  = (const float*)d_in[4];
  const float* W_UQ  = (const float*)d_in[5];
  const float* W_QR  = (const float*)d_in[6];
  const float* W_KR  = (const float*)d_in[7];
  const float* W_O   = (const float*)d_in[8];
  const float* s_qk  = (const float*)d_in[9];

  char* base = (char*)d_ws;
  // static layout (bytes) — high-water mark 232,259,584 B (221.5 MiB):
  u16* xb     = (u16*)(base);                        // [0, 33,554,432)           dead after G_KR
  u16* WtDKVQ = (u16*)(base + (size_t)33554432);     // [.., 41,943,040)  8.39 MB dead after G1
  u16* WtUKV  = (u16*)(base + (size_t)41943040);     // [.., 58,720,256) 16.78 MB dead after G2
  u16* WtUQR  = (u16*)(base + (size_t)58720256);     // [.., 71,303,168) 12.58 MB dead after G3
  u16* WtKR   = (u16*)(base + (size_t)71303168);     // [.., 71,827,456)  0.52 MB dead after G_KR
  u16* WtO    = (u16*)(base + (size_t)71827456);     // [.., 80,216,064)  8.39 MB live to end
  u16* ckvq   = (u16*)(base + (size_t)80216064);     // [.., 113,770,496) 33.55 MB dead after G3
  u16* kcv    = (u16*)(base + (size_t)113770496);    // [.., 180,879,360) 67.11 MB dead after transpose_v
  u16* qcr    = (u16*)(base + (size_t)180879360);    // [.., 231,211,008) 50.33 MB dead after build_q
  u16* kr     = (u16*)(base + (size_t)231211008);    // [.., 232,259,584)  1.05 MB
  // aliases (each writer runs strictly after the aliased region's last reader):
  u16* qn = (u16*)(base);      // 50.33 MB over xb+WtDKVQ+WtUKV (all dead before build_q)
  u16* kn = qcr;               // 50.33 MB, exact size match; build_k runs after build_q
  u16* Vt = ckvq;              // 33.55 MB over ckvq (dead after G3)
  u16* O  = kcv;               // 33.55 MB over kcv head (dead after transpose_v)

  // 1) casts / weight transposes (into merged layouts)
  cast_f32_bf16<<<16384, 256, 0, stream>>>(x, xb, 8192 * 2048 / 4);
  transpose_cast<<<dim3(16, 32), 256, 0, stream>>>(W_DKV, WtDKVQ,                  2048, 1024);
  transpose_cast<<<dim3(16, 32), 256, 0, stream>>>(W_DQ,  WtDKVQ + 1024 * 2048,    2048, 1024);
  transpose_cast<<<dim3(32, 16), 256, 0, stream>>>(W_UK,  WtUKV,                   1024, 2048);
  transpose_cast<<<dim3(32, 16), 256, 0, stream>>>(W_UV,  WtUKV + 2048 * 1024,     1024, 2048);
  transpose_cast<<<dim3(32, 16), 256, 0, stream>>>(W_UQ,  WtUQR,                   1024, 2048);
  transpose_cast<<<dim3(16, 16), 256, 0, stream>>>(W_QR,  WtUQR + 2048 * 1024,     1024, 1024);
  transpose_cast<<<dim3(1, 32),  256, 0, stream>>>(W_KR,  WtKR,                    2048, 64);
  transpose_cast<<<dim3(32, 32), 256, 0, stream>>>(W_O,   WtO,                     2048, 2048);

  // 2) merged projection GEMMs
  gemm_bt<u16><<<dim3(16, 64), 256, 0, stream>>>(xb, 2048, WtDKVQ, ckvq, 2048, 8192, 2048, 2048);
  gemm_bt<u16><<<dim3(1, 64),  256, 0, stream>>>(xb, 2048, WtKR, kr, 64, 8192, 64, 2048);
  gemm_bt<u16><<<dim3(32, 64), 256, 0, stream>>>(ckvq, 2048, WtUKV, kcv, 4096, 8192, 4096, 1024);
  gemm_bt<u16><<<dim3(24, 64), 256, 0, stream>>>(ckvq + 1024, 2048, WtUQR, qcr, 3072, 8192, 3072, 1024);

  // 3) rope + concat + normalize (build_q consumes qcr, THEN build_k writes kn over it)
  build_q<<<32768, 256, 0, stream>>>(qcr, s_qk, qn);
  build_k<<<32768, 256, 0, stream>>>(kcv, kr, kn);

  // 4) V transpose (Vt over dead ckvq region)
  transpose_v<<<dim3(32, 2, 64), 256, 0, stream>>>(kcv, Vt);

  // 5) attention: 512 blocks x 512 thr, 256 q-rows/block, static-max softmax
  flash_attn<<<dim3(512), 512, 0, stream>>>(qn, kn, Vt, s_qk, O);

  // 6) output projection -> fp32 d_out
  gemm_bt<float><<<dim3(16, 64), 256, 0, stream>>>(O, 2048, WtO, (float*)d_out, 2048, 8192, 2048, 2048);
}

// Round 2
// 792.289 us; speedup vs baseline: 1.6066x; 1.2113x over previous
//
#include <hip/hip_runtime.h>
#include <stdint.h>

typedef unsigned short u16;
typedef unsigned int u32;
typedef short bf16x8 __attribute__((ext_vector_type(8)));
typedef float f32x4 __attribute__((ext_vector_type(4)));
typedef u16 u16x4 __attribute__((ext_vector_type(4)));

#define DEV __device__ __forceinline__

DEV float bf2f(u16 u) { union { float f; u32 i; } x; x.i = ((u32)u) << 16; return x.f; }
DEV u16 f2bf(float f) {
  union { float f; u32 i; } x; x.f = f;
  u32 i = x.i;
  u32 r = (i + 0x7fffu + ((i >> 16) & 1u)) >> 16;  // RTNE
  return (u16)r;
}

// async global->LDS, 16B per lane. lds base must be wave-uniform; HW adds lane*16.
DEV void gl_lds16(const u16* g, u16* l) {
  __builtin_amdgcn_global_load_lds((const __attribute__((address_space(1))) u32*)g,
                                   (__attribute__((address_space(3))) u32*)l, 16, 0, 0);
}

// ---------------- cast fp32 -> bf16 (vectorized) ----------------
__global__ __launch_bounds__(256) void cast_f32_bf16(const float* __restrict__ in,
                                                     u16* __restrict__ out, int n4) {
  int i = blockIdx.x * 256 + threadIdx.x;
  if (i >= n4) return;
  float4 v = ((const float4*)in)[i];
  u16x4 o;
  o.x = f2bf(v.x); o.y = f2bf(v.y); o.z = f2bf(v.z); o.w = f2bf(v.w);
  ((u16x4*)out)[i] = o;
}

// ---------------- transpose + cast: W (K,N) fp32 -> Wt (N,K) bf16 ----------------
__global__ __launch_bounds__(256) void transpose_cast(const float* __restrict__ W,
                                                      u16* __restrict__ Wt, int K, int N) {
  __shared__ float tile[64][65];
  int n0 = blockIdx.x * 64;
  int k0 = blockIdx.y * 64;
#pragma unroll
  for (int i = 0; i < 16; ++i) {
    int idx = threadIdx.x + i * 256;
    int r = idx >> 6, c = idx & 63;             // r: k-off, c: n-off
    tile[r][c] = W[(size_t)(k0 + r) * N + n0 + c];
  }
  __syncthreads();
#pragma unroll
  for (int i = 0; i < 16; ++i) {
    int idx = threadIdx.x + i * 256;
    int r = idx >> 6, c = idx & 63;             // r: n-off, c: k-off
    Wt[(size_t)(n0 + r) * K + k0 + c] = f2bf(tile[c][r]);
  }
}

// ---------------- transpose V: rows of kcv (B*L, 4096), v = cols 2048+h*128+dv -> Vt (B,H,128,L) ----------------
__global__ __launch_bounds__(256) void transpose_v(const u16* __restrict__ KCV,
                                                   u16* __restrict__ Vt) {
  __shared__ float tile[64][65];
  int l0 = blockIdx.x * 64;   // 32 tiles over L
  int d0 = blockIdx.y * 64;   // 2 tiles over 128
  int bh = blockIdx.z;        // b*16+h
  int b = bh >> 4, h = bh & 15;
#pragma unroll
  for (int i = 0; i < 16; ++i) {
    int idx = threadIdx.x + i * 256;
    int r = idx >> 6, c = idx & 63;
    tile[r][c] = bf2f(KCV[(size_t)(b * 2048 + l0 + r) * 4096 + 2048 + h * 128 + d0 + c]);
  }
  __syncthreads();
#pragma unroll
  for (int i = 0; i < 16; ++i) {
    int idx = threadIdx.x + i * 256;
    int rr = idx >> 6, cc = idx & 63;  // rr: dv-off, cc: l-off
    Vt[((size_t)bh * 128 + d0 + rr) * 2048 + l0 + cc] = f2bf(tile[cc][rr]);
  }
}

// ---------------- GEMM: C(MxN) = A(MxK bf16, row-stride lda) * Bt(NxK bf16)^T ----------------
DEV void ep_set(u16* E, int i, float v) { E[i] = f2bf(v); }
DEV void ep_set(float* E, int i, float v) { E[i] = v; }

template <typename OT>
__global__ __launch_bounds__(256) void gemm_bt(const u16* __restrict__ A, int lda,
                                               const u16* __restrict__ Bt,
                                               OT* __restrict__ C, int ldc,
                                               int M, int N, int K) {
  __shared__ u16 smem_ab[2 * 128 * 32];   // As | Bs (contiguous 16KB; reused by epilogue)
  u16* As = smem_ab;
  u16* Bs = smem_ab + 128 * 32;
  const int tid = threadIdx.x;
  const int lane = tid & 63;
  const int w = tid >> 6;       // 0..3
  const int quad = lane >> 4;   // 0..3
  const int l15 = lane & 15;
  // T1 bijective XCD swizzle (all grids have nwg % 8 == 0): each XCD gets a
  // contiguous chunk of the grid -> A-panel L2 locality.
  const int nwg = gridDim.x * gridDim.y;
  const int lin = blockIdx.y * gridDim.x + blockIdx.x;
  const int swz = (lin & 7) * (nwg >> 3) + (lin >> 3);
  const int m0 = (swz / gridDim.x) * 128;
  const int n0 = (swz % gridDim.x) * 128;
  const int wm = (w & 1) * 64;
  const int wn = (w >> 1) * 64;

  f32x4 acc[4][4] = {};

  for (int k0 = 0; k0 < K; k0 += 32) {
#pragma unroll
    for (int it = 0; it < 2; ++it) {
      int ca = w * 128 + it * 64;       // wave-uniform base chunk
      int c = ca + lane;
      int row = c >> 2, kc = (c & 3) * 8;
      gl_lds16(A + (size_t)(m0 + row) * lda + k0 + kc, &As[ca * 8]);
      gl_lds16(Bt + (size_t)(n0 + row) * K + k0 + kc, &Bs[ca * 8]);
    }
    __syncthreads();   // waits vmcnt(0) for global_load_lds
    bf16x8 af[4], bf[4];
#pragma unroll
    for (int mt = 0; mt < 4; ++mt) af[mt] = *(const bf16x8*)&As[(wm + mt * 16 + l15) * 32 + quad * 8];
#pragma unroll
    for (int nt = 0; nt < 4; ++nt) bf[nt] = *(const bf16x8*)&Bs[(wn + nt * 16 + l15) * 32 + quad * 8];
#pragma unroll
    for (int mt = 0; mt < 4; ++mt)
#pragma unroll
      for (int nt = 0; nt < 4; ++nt)
        acc[mt][nt] = __builtin_amdgcn_mfma_f32_16x16x32_bf16(af[mt], bf[nt], acc[mt][nt], 0, 0, 0);
    __syncthreads();
  }

  // wide-store epilogue through LDS (smem_ab free after final barrier).
  // Wave-private region -> only lgkmcnt fences needed (DS ops are in-order per wave).
  OT* Ew = ((OT*)smem_ab) + w * 1024;   // 16 rows x 64 cols per wave
#pragma unroll
  for (int mt = 0; mt < 4; ++mt) {
#pragma unroll
    for (int nt = 0; nt < 4; ++nt)
#pragma unroll
      for (int r = 0; r < 4; ++r)
        ep_set(Ew, (quad * 4 + r) * 64 + nt * 16 + l15, acc[mt][nt][r]);
    asm volatile("s_waitcnt lgkmcnt(0)" ::: "memory");
#pragma unroll
    for (int it2 = 0; it2 < 4; ++it2) {
      int row_i = it2 * 4 + quad;
      int colg = n0 + wn + l15 * 4;
      if (colg < N) {   // only trims for the N=64 (W_KR) GEMM
        size_t off = (size_t)(m0 + wm + mt * 16 + row_i) * ldc + colg;
        if constexpr (sizeof(OT) == 2) {
          *(u16x4*)&C[off] = *(const u16x4*)&Ew[row_i * 64 + l15 * 4];
        } else {
          *(float4*)&C[off] = *(const float4*)&Ew[row_i * 64 + l15 * 4];
        }
      }
    }
  }
}

// ---------------- build q / k: rope + concat + L2-normalize, one wave per (token, head) ----------------
// fast trig: freq = exp(-j*ln(10000)/32) via v_exp; __sinf/__cosf (HW v_sin/v_cos),
// error ~1e-4 rad at max arg 2047 -- far below bf16 rounding.
__global__ __launch_bounds__(256) void build_q(const u16* __restrict__ qcr,  // (B*L, 3072): qc|qr
                                               const float* __restrict__ s_qk,
                                               u16* __restrict__ qn) {
  const int wid = blockIdx.x * 4 + (threadIdx.x >> 6);
  const int lane = threadIdx.x & 63;
  const int token = wid >> 4;     // b*L + l
  const int h = wid & 15;
  const int b = token >> 11;
  const int l = token & 2047;
  float v0 = bf2f(qcr[(size_t)token * 3072 + h * 128 + lane]);
  float v1 = bf2f(qcr[(size_t)token * 3072 + h * 128 + 64 + lane]);
  int j = lane & 31;
  float freq = __expf((float)j * -0.28782313662425574f);   // 10000^(-j/32)
  float ang = (float)l * freq;
  float cs = __cosf(ang), sn = __sinf(ang);
  float xr = bf2f(qcr[(size_t)token * 3072 + 2048 + h * 64 + lane]);
  float xo = bf2f(qcr[(size_t)token * 3072 + 2048 + h * 64 + (lane ^ 32)]);
  float v2 = (lane < 32) ? (xr * cs - xo * sn) : (xr * cs + xo * sn);
  float ss = v0 * v0 + v1 * v1 + v2 * v2;
#pragma unroll
  for (int off = 1; off < 64; off <<= 1) ss += __shfl_xor(ss, off, 64);
  float scale = s_qk[0] / fmaxf(sqrtf(ss), 1e-12f);
  u16* out = qn + (((size_t)(b * 16 + h) * 2048) + l) * 192;
  out[lane] = f2bf(v0 * scale);
  out[64 + lane] = f2bf(v1 * scale);
  out[128 + lane] = f2bf(v2 * scale);
}

__global__ __launch_bounds__(256) void build_k(const u16* __restrict__ kcv,  // (B*L, 4096): kc|v
                                               const u16* __restrict__ krr,  // (B*L, 64)
                                               u16* __restrict__ kn) {
  const int wid = blockIdx.x * 4 + (threadIdx.x >> 6);
  const int lane = threadIdx.x & 63;
  const int token = wid >> 4;
  const int h = wid & 15;
  const int b = token >> 11;
  const int l = token & 2047;
  float v0 = bf2f(kcv[(size_t)token * 4096 + h * 128 + lane]);
  float v1 = bf2f(kcv[(size_t)token * 4096 + h * 128 + 64 + lane]);
  int j = lane & 31;
  float freq = __expf((float)j * -0.28782313662425574f);   // 10000^(-j/32)
  float ang = (float)l * freq;
  float cs = __cosf(ang), sn = __sinf(ang);
  float xr = bf2f(krr[(size_t)token * 64 + lane]);
  float xo = bf2f(krr[(size_t)token * 64 + (lane ^ 32)]);
  float v2 = (lane < 32) ? (xr * cs - xo * sn) : (xr * cs + xo * sn);
  float ss = v0 * v0 + v1 * v1 + v2 * v2;
#pragma unroll
  for (int off = 1; off < 64; off <<= 1) ss += __shfl_xor(ss, off, 64);
  float scale = 1.0f / fmaxf(sqrtf(ss), 1e-12f);
  u16* out = kn + (((size_t)(b * 16 + h) * 2048) + l) * 192;
  out[lane] = f2bf(v0 * scale);
  out[64 + lane] = f2bf(v1 * scale);
  out[128 + lane] = f2bf(v2 * scale);
}

// ---------------- flash attention (causal), 512 thr, balanced pairing ----------------
// 256 blocks (1/CU): block handles q-tiles {7-pairIdx, pairIdx} -> constant 36
// 64-key tiles/block, zero tail, no second dispatch round.
// Static-max softmax (q,k unit-norm, q pre-scaled by s_qk => score <= s_qk);
// denominator via ones-MFMA; no running max, no rescale, no cross-lane reduce.
// KVBLK=64: one barrier per 64 keys (~100 MFMA between barriers). K and V both
// XOR-swizzled in LDS (pre-swizzled global source, swizzled read) -> <=2-way
// bank conflicts on ds_read_b128. setprio(1) around MFMA clusters (T5).
__global__ __launch_bounds__(512, 2) void flash_attn(const u16* __restrict__ Q,   // (B,H,L,192)
                                                     const u16* __restrict__ Kn,  // (B,H,L,192)
                                                     const u16* __restrict__ Vt,  // (B,H,128,L)
                                                     const float* __restrict__ s_qk,
                                                     u16* __restrict__ O) {       // (B,L,2048)
  constexpr int L = 2048, DQK = 192, DV = 128, KVB = 64;
  constexpr int PSTR = 72;
  __shared__ u16 smem[59392];          // Ks[2][64*192] | Vs[2][128*64] | Ps[8*32*72] = 118784 B
  u16* KsBuf = smem;                   // 2 x 12288 u16
  u16* VsBuf = smem + 24576;           // 2 x 8192 u16
  u16* Ps    = smem + 40960;           // 18432 u16
  const int tid = threadIdx.x;
  const int lane = tid & 63;
  const int w = tid >> 6;       // 0..7, q-row group (32 rows each)
  const int quad = lane >> 4;
  const int l15 = lane & 15;
  // 256 blocks: xcd = lin&7; all 4 pair-blocks of a bh share an XCD (K/V L2 reuse)
  const int lin = blockIdx.x;
  const int xcd = lin & 7;
  const int g = lin >> 3;         // 0..31
  const int bh = ((g >> 2) << 3) | xcd;
  const int pairIdx = g & 3;      // qtA = 7-pairIdx, qtB = pairIdx -> 36 tiles each
  const int b = bh >> 4, h = bh & 15;
  const float SMAX = s_qk[0];     // upper bound on every score

  const u16* Kg = Kn + (size_t)bh * L * DQK;
  const u16* Vg = Vt + (size_t)bh * DV * L;

  // stage one 64-key K/V tile. K: 64 rows x 24 chunks (16B) = 1536, V: 128 dv x 8
  // chunks = 1024; 2560 chunks = 5 x 512 lanes. LDS dest linear; global source
  // column pre-swizzled (c = cp ^ (row&7)) for both K and V (rule #21).
  auto stage = [&](int kt2, int bufi) {
    u16* KsB = KsBuf + bufi * 12288;
    u16* VsB = VsBuf + bufi * 8192;
#pragma unroll
    for (int it = 0; it < 5; ++it) {
      int B0 = it * 512 + w * 64;            // wave-uniform, 64-aligned
      if (B0 < 1536) {
        int p = B0 + lane;
        int r = p / 24, cp = p % 24;
        int c = cp ^ (r & 7);                // XOR stays within 0..23 (low-3-bit)
        gl_lds16(Kg + (size_t)(kt2 * KVB + r) * DQK + c * 8, &KsB[B0 * 8]);
      } else {
        int p = B0 - 1536 + lane;
        int dv = p >> 3, cp = p & 7;
        int c = cp ^ (dv & 7);
        gl_lds16(Vg + (size_t)dv * L + kt2 * KVB + c * 8, &VsB[(B0 - 1536) * 8]);
      }
    }
  };

  bf16x8 ones;
#pragma unroll
  for (int j = 0; j < 8; ++j) ones[j] = (short)0x3F80;   // bf16 1.0

  for (int qp = 0; qp < 2; ++qp) {
    const int qt = (qp == 0) ? (7 - pairIdx) : pairIdx;
    const u16* Qg = Q + ((size_t)bh * L + qt * 256) * DQK;

    // Q fragments: wave w owns q rows w*32 .. w*32+31 (two m-frags)
    bf16x8 qf[2][6];
#pragma unroll
    for (int mt = 0; mt < 2; ++mt)
#pragma unroll
      for (int kd = 0; kd < 6; ++kd)
        qf[mt][kd] = *(const bf16x8*)&Qg[(w * 32 + mt * 16 + l15) * DQK + kd * 32 + quad * 8];

    f32x4 oacc[2][8] = {};
    f32x4 accL[2] = {};           // running row-sum of P via ones-MFMA

    const int nkv = 4 * (qt + 1);   // 64-key tiles
    stage(0, 0);
    __syncthreads();

    for (int kt = 0; kt < nkv; ++kt) {
      const int cur = kt & 1;
      if (kt + 1 < nkv) stage(kt + 1, cur ^ 1);   // prefetch overlaps compute
      const u16* KsC = KsBuf + cur * 12288;
      const u16* VsC = VsBuf + cur * 8192;

      // S (2 x 16q x 64k) per wave; K reads shared across both m-frags
      f32x4 s[2][4] = {};
      __builtin_amdgcn_s_setprio(1);
#pragma unroll
      for (int kd = 0; kd < 6; ++kd) {
#pragma unroll
        for (int nt = 0; nt < 4; ++nt) {
          int row = nt * 16 + l15;
          int cp = (kd * 4 + quad) ^ (l15 & 7);
          bf16x8 bb = *(const bf16x8*)&KsC[row * DQK + cp * 8];
#pragma unroll
          for (int mt = 0; mt < 2; ++mt)
            s[mt][nt] = __builtin_amdgcn_mfma_f32_16x16x32_bf16(qf[mt][kd], bb, s[mt][nt], 0, 0, 0);
        }
      }
      __builtin_amdgcn_s_setprio(0);

      // causal mask + static-max exp, P -> per-wave LDS (C-layout scatter)
      const int kcol0 = kt * KVB + l15;
      u16* Pw = &Ps[w * 32 * PSTR];
#pragma unroll
      for (int mt = 0; mt < 2; ++mt) {
        const int qrow_base = qt * 256 + w * 32 + mt * 16 + quad * 4;
#pragma unroll
        for (int r = 0; r < 4; ++r)
#pragma unroll
          for (int nt = 0; nt < 4; ++nt) {
            float p = (kcol0 + nt * 16 > qrow_base + r) ? 0.f : __expf(s[mt][nt][r] - SMAX);
            Pw[(mt * 16 + quad * 4 + r) * PSTR + nt * 16 + l15] = f2bf(p);
          }
      }
      asm volatile("s_waitcnt lgkmcnt(0)" ::: "memory");  // within-wave WAR/RAW order

      // A-layout P reads; l via ones-MFMA; V reads (swizzled) shared across m-frags
      __builtin_amdgcn_s_setprio(1);
      bf16x8 pf[2][2];
#pragma unroll
      for (int mt = 0; mt < 2; ++mt)
#pragma unroll
        for (int kc = 0; kc < 2; ++kc) {
          pf[mt][kc] = *(const bf16x8*)&Pw[(mt * 16 + l15) * PSTR + kc * 32 + quad * 8];
          accL[mt] = __builtin_amdgcn_mfma_f32_16x16x32_bf16(pf[mt][kc], ones, accL[mt], 0, 0, 0);
        }
#pragma unroll
      for (int nt2 = 0; nt2 < 8; ++nt2) {
        const int dv = nt2 * 16 + l15;
#pragma unroll
        for (int kc = 0; kc < 2; ++kc) {
          int lc = (kc * 4 + quad) ^ (l15 & 7);   // dv&7 == l15&7
          bf16x8 vv = *(const bf16x8*)&VsC[dv * KVB + lc * 8];
#pragma unroll
          for (int mt = 0; mt < 2; ++mt)
            oacc[mt][nt2] = __builtin_amdgcn_mfma_f32_16x16x32_bf16(pf[mt][kc], vv, oacc[mt][nt2], 0, 0, 0);
        }
      }
      __builtin_amdgcn_s_setprio(0);
      __syncthreads();  // drains prefetch (vmcnt) + frees cur buffer
    }

    // epilogue: wide O store via LDS transpose (smem front free after last barrier)
    float rinv[2][4];
#pragma unroll
    for (int mt = 0; mt < 2; ++mt)
#pragma unroll
      for (int r = 0; r < 4; ++r) rinv[mt][r] = 1.0f / accL[mt][r];
    u16* Ew = smem + w * 2048;    // 16 rows x 128 cols per wave (8 waves = 32KB)
#pragma unroll
    for (int mt = 0; mt < 2; ++mt) {
#pragma unroll
      for (int nt2 = 0; nt2 < 8; ++nt2)
#pragma unroll
        for (int r = 0; r < 4; ++r)
          Ew[(quad * 4 + r) * 128 + nt2 * 16 + l15] = f2bf(oacc[mt][nt2][r] * rinv[mt][r]);
      asm volatile("s_waitcnt lgkmcnt(0)" ::: "memory");
#pragma unroll
      for (int it2 = 0; it2 < 4; ++it2) {
        int row_i = it2 * 4 + quad;
        int lg = qt * 256 + w * 32 + mt * 16 + row_i;
        uint4 v = *(const uint4*)&Ew[row_i * 128 + l15 * 8];
        *(uint4*)&O[((size_t)b * L + lg) * 2048 + h * 128 + l15 * 8] = v;
      }
    }
    __syncthreads();   // protect Ew region before next pass's stage(0,0)
  }
}

// ---------------- launcher ----------------
extern "C" void kernel_launch(void* const* d_in, const int* in_sizes, int n_in,
                              void* d_out, int out_size, void* d_ws, size_t ws_size,
                              hipStream_t stream) {
  const float* x     = (const float*)d_in[0];
  const float* W_DKV = (const float*)d_in[1];
  const float* W_UK  = (const float*)d_in[2];
  const float* W_UV  = (const float*)d_in[3];
  const float* W_DQ  = (const float*)d_in[4];
  const float* W_UQ  = (const float*)d_in[5];
  const float* W_QR  = (const float*)d_in[6];
  const float* W_KR  = (const float*)d_in[7];
  const float* W_O   = (const float*)d_in[8];
  const float* s_qk  = (const float*)d_in[9];

  char* base = (char*)d_ws;
  // static layout (bytes) — high-water mark 232,259,584 B (221.5 MiB):
  u16* xb     = (u16*)(base);                        // [0, 33,554,432)           dead after G_KR
  u16* WtDKVQ = (u16*)(base + (size_t)33554432);     // [.., 41,943,040)  8.39 MB dead after G1
  u16* WtUKV  = (u16*)(base + (size_t)41943040);     // [.., 58,720,256) 16.78 MB dead after G2
  u16* WtUQR  = (u16*)(base + (size_t)58720256);     // [.., 71,303,168) 12.58 MB dead after G3
  u16* WtKR   = (u16*)(base + (size_t)71303168);     // [.., 71,827,456)  0.52 MB dead after G_KR
  u16* WtO    = (u16*)(base + (size_t)71827456);     // [.., 80,216,064)  8.39 MB live to end
  u16* ckvq   = (u16*)(base + (size_t)80216064);     // [.., 113,770,496) 33.55 MB dead after G3
  u16* kcv    = (u16*)(base + (size_t)113770496);    // [.., 180,879,360) 67.11 MB dead after transpose_v
  u16* qcr    = (u16*)(base + (size_t)180879360);    // [.., 231,211,008) 50.33 MB dead after build_q
  u16* kr     = (u16*)(base + (size_t)231211008);    // [.., 232,259,584)  1.05 MB
  // aliases (each writer runs strictly after the aliased region's last reader):
  u16* qn = (u16*)(base);      // 50.33 MB over xb+WtDKVQ+WtUKV (all dead before build_q)
  u16* kn = qcr;               // 50.33 MB, exact size match; build_k runs after build_q
  u16* Vt = ckvq;              // 33.55 MB over ckvq (dead after G3)
  u16* O  = kcv;               // 33.55 MB over kcv head (dead after transpose_v)

  // 1) casts / weight transposes (into merged layouts)
  cast_f32_bf16<<<16384, 256, 0, stream>>>(x, xb, 8192 * 2048 / 4);
  transpose_cast<<<dim3(16, 32), 256, 0, stream>>>(W_DKV, WtDKVQ,                  2048, 1024);
  transpose_cast<<<dim3(16, 32), 256, 0, stream>>>(W_DQ,  WtDKVQ + 1024 * 2048,    2048, 1024);
  transpose_cast<<<dim3(32, 16), 256, 0, stream>>>(W_UK,  WtUKV,                   1024, 2048);
  transpose_cast<<<dim3(32, 16), 256, 0, stream>>>(W_UV,  WtUKV + 2048 * 1024,     1024, 2048);
  transpose_cast<<<dim3(32, 16), 256, 0, stream>>>(W_UQ,  WtUQR,                   1024, 2048);
  transpose_cast<<<dim3(16, 16), 256, 0, stream>>>(W_QR,  WtUQR + 2048 * 1024,     1024, 1024);
  transpose_cast<<<dim3(1, 32),  256, 0, stream>>>(W_KR,  WtKR,                    2048, 64);
  transpose_cast<<<dim3(32, 32), 256, 0, stream>>>(W_O,   WtO,                     2048, 2048);

  // 2) merged projection GEMMs
  gemm_bt<u16><<<dim3(16, 64), 256, 0, stream>>>(xb, 2048, WtDKVQ, ckvq, 2048, 8192, 2048, 2048);
  gemm_bt<u16><<<dim3(1, 64),  256, 0, stream>>>(xb, 2048, WtKR, kr, 64, 8192, 64, 2048);
  gemm_bt<u16><<<dim3(32, 64), 256, 0, stream>>>(ckvq, 2048, WtUKV, kcv, 4096, 8192, 4096, 1024);
  gemm_bt<u16><<<dim3(24, 64), 256, 0, stream>>>(ckvq + 1024, 2048, WtUQR, qcr, 3072, 8192, 3072, 1024);

  // 3) rope + concat + normalize (build_q consumes qcr, THEN build_k writes kn over it)
  build_q<<<32768, 256, 0, stream>>>(qcr, s_qk, qn);
  build_k<<<32768, 256, 0, stream>>>(kcv, kr, kn);

  // 4) V transpose (Vt over dead ckvq region)
  transpose_v<<<dim3(32, 2, 64), 256, 0, stream>>>(kcv, Vt);

  // 5) attention: 256 blocks x 512 thr, balanced q-tile pairs, 64-key tiles
  flash_attn<<<dim3(256), 512, 0, stream>>>(qn, kn, Vt, s_qk, O);

  // 6) output projection -> fp32 d_out
  gemm_bt<float><<<dim3(16, 64), 256, 0, stream>>>(O, 2048, WtO, (float*)d_out, 2048, 8192, 2048, 2048);
}

// Round 3
// 678.198 us; speedup vs baseline: 1.8769x; 1.1682x over previous
//
#include <hip/hip_runtime.h>
#include <stdint.h>

typedef unsigned short u16;
typedef unsigned int u32;
typedef short bf16x8 __attribute__((ext_vector_type(8)));
typedef float f32x4 __attribute__((ext_vector_type(4)));
typedef u16 u16x4 __attribute__((ext_vector_type(4)));

#define DEV __device__ __forceinline__

DEV float bf2f(u16 u) { union { float f; u32 i; } x; x.i = ((u32)u) << 16; return x.f; }
DEV u16 f2bf(float f) {
  union { float f; u32 i; } x; x.f = f;
  u32 i = x.i;
  u32 r = (i + 0x7fffu + ((i >> 16) & 1u)) >> 16;  // RTNE
  return (u16)r;
}

// async global->LDS, 16B per lane. lds base must be wave-uniform; HW adds lane*16.
DEV void gl_lds16(const u16* g, u16* l) {
  __builtin_amdgcn_global_load_lds((const __attribute__((address_space(1))) u32*)g,
                                   (__attribute__((address_space(3))) u32*)l, 16, 0, 0);
}

// ---------------- cast fp32 -> bf16 (vectorized) ----------------
__global__ __launch_bounds__(256) void cast_f32_bf16(const float* __restrict__ in,
                                                     u16* __restrict__ out, int n4) {
  int i = blockIdx.x * 256 + threadIdx.x;
  if (i >= n4) return;
  float4 v = ((const float4*)in)[i];
  u16x4 o;
  o.x = f2bf(v.x); o.y = f2bf(v.y); o.z = f2bf(v.z); o.w = f2bf(v.w);
  ((u16x4*)out)[i] = o;
}

// ---------------- transpose + cast: W (K,N) fp32 -> Wt (N,K) bf16 ----------------
__global__ __launch_bounds__(256) void transpose_cast(const float* __restrict__ W,
                                                      u16* __restrict__ Wt, int K, int N) {
  __shared__ float tile[64][65];
  int n0 = blockIdx.x * 64;
  int k0 = blockIdx.y * 64;
#pragma unroll
  for (int i = 0; i < 16; ++i) {
    int idx = threadIdx.x + i * 256;
    int r = idx >> 6, c = idx & 63;             // r: k-off, c: n-off
    tile[r][c] = W[(size_t)(k0 + r) * N + n0 + c];
  }
  __syncthreads();
#pragma unroll
  for (int i = 0; i < 16; ++i) {
    int idx = threadIdx.x + i * 256;
    int r = idx >> 6, c = idx & 63;             // r: n-off, c: k-off
    Wt[(size_t)(n0 + r) * K + k0 + c] = f2bf(tile[c][r]);
  }
}

// ---------------- transpose V: rows of kcv (B*L, 4096), v = cols 2048+h*128+dv -> Vt (B,H,128,L) ----------------
__global__ __launch_bounds__(256) void transpose_v(const u16* __restrict__ KCV,
                                                   u16* __restrict__ Vt) {
  __shared__ float tile[64][65];
  int l0 = blockIdx.x * 64;   // 32 tiles over L
  int d0 = blockIdx.y * 64;   // 2 tiles over 128
  int bh = blockIdx.z;        // b*16+h
  int b = bh >> 4, h = bh & 15;
#pragma unroll
  for (int i = 0; i < 16; ++i) {
    int idx = threadIdx.x + i * 256;
    int r = idx >> 6, c = idx & 63;
    tile[r][c] = bf2f(KCV[(size_t)(b * 2048 + l0 + r) * 4096 + 2048 + h * 128 + d0 + c]);
  }
  __syncthreads();
#pragma unroll
  for (int i = 0; i < 16; ++i) {
    int idx = threadIdx.x + i * 256;
    int rr = idx >> 6, cc = idx & 63;  // rr: dv-off, cc: l-off
    Vt[((size_t)bh * 128 + d0 + rr) * 2048 + l0 + cc] = f2bf(tile[cc][rr]);
  }
}

DEV void ep_set(u16* E, int i, float v) { E[i] = f2bf(v); }
DEV void ep_set(float* E, int i, float v) { E[i] = v; }

// ---------------- GEMM 256x256 8-phase (T2+T3+T4+T5): C = A(MxK) * Bt(NxK)^T ----------------
// 8 waves (2M x 4N), per-wave 128x64 out. BK=64 split into 2 k-halves; staging
// unit = one operand k-half [256][32] (16KB = 2 gl_lds16/thread). Phase (ks,mq):
// 8 ds_read_b128 + 1 unit stage + 16 MFMA between raw barriers. Counted
// s_waitcnt vmcnt(4) once per K-tile (2 newest units may fly) -- never 0.
// LDS XOR-swizzle chunk' = quad ^ ((l15>>1)&3) on reads, inverse-applied on the
// global source column during staging (linear LDS dest, rule both-sides).
// M, N multiples of 256; K multiple of 64; K >= 128.
template <typename OT>
__global__ __launch_bounds__(512, 2) void gemm256(const u16* __restrict__ A, int lda,
                                                  const u16* __restrict__ Bt,
                                                  OT* __restrict__ C, int ldc, int K) {
  __shared__ u16 smem[65536];   // 128KB: buf[t&1]{ A[2][256][32] | B[2][256][32] }
  const int tid = threadIdx.x;
  const int lane = tid & 63;
  const int w = tid >> 6;       // 0..7
  const int wm = w >> 2;        // 0..1 (M)
  const int wn = w & 3;         // 0..3 (N)
  const int quad = lane >> 4;
  const int l15 = lane & 15;
  const int cs = quad ^ ((l15 >> 1) & 3);   // swizzled k-chunk for frag reads
  // T1 bijective XCD swizzle (nwg % 8 == 0 for all our grids)
  const int nwg = gridDim.x * gridDim.y;
  const int lin = blockIdx.y * gridDim.x + blockIdx.x;
  const int swz = (lin & 7) * (nwg >> 3) + (lin >> 3);
  const int m0 = (swz / gridDim.x) * 256;
  const int n0 = (swz % gridDim.x) * 256;

  // staging per-thread geometry: thread covers row rloc (of 128 per issue),
  // phys chunk tid&3; logical chunk = phys ^ ((row>>1)&3).
  const int rloc = tid >> 2;                       // 0..127
  const int clog = (tid & 3) ^ ((tid >> 3) & 3);   // pre-swizzled source column
  const size_t aoff0 = (size_t)rloc * lda + clog * 8;
  const size_t boff0 = (size_t)rloc * (size_t)K + clog * 8;
  const u16* Ag = A + (size_t)m0 * lda;
  const u16* Bg = Bt + (size_t)n0 * K;

  auto stageA = [&](int u, int ks2) {
    u16* dst = smem + (u & 1) * 32768 + ks2 * 8192 + w * 512;
    const u16* s0 = Ag + aoff0 + u * 64 + ks2 * 32;
    gl_lds16(s0, dst);
    gl_lds16(s0 + (size_t)128 * lda, dst + 4096);
  };
  auto stageB = [&](int u, int ks2) {
    u16* dst = smem + (u & 1) * 32768 + 16384 + ks2 * 8192 + w * 512;
    const u16* s0 = Bg + boff0 + u * 64 + ks2 * 32;
    gl_lds16(s0, dst);
    gl_lds16(s0 + (size_t)128 * (size_t)K, dst + 4096);
  };

  f32x4 acc[2][4][4] = {};   // [mq][mt][n], all indices compile-time (rule #20)
  const int nt = K >> 6;

  // prologue: tile0 fully + tile1 k-half0 (12 loads); wait until only the 4
  // newest (t1 ks0) may be outstanding -> tile0 resident.
  stageA(0, 0); stageB(0, 0); stageA(0, 1); stageB(0, 1);
  stageA(1, 0); stageB(1, 0);
  asm volatile("s_waitcnt vmcnt(4)" ::: "memory");
  __builtin_amdgcn_s_barrier();

  for (int t = 0; t < nt; ++t) {
    const u16* As_ = smem + (t & 1) * 32768;
    const u16* Bs_ = As_ + 16384;
#pragma unroll
    for (int p = 0; p < 4; ++p) {
      const int ks = p >> 1;
      const int mq = p & 1;
      const u16* Ab = As_ + ks * 8192;
      const u16* Bb = Bs_ + ks * 8192;
      bf16x8 af[4], bf[4];
#pragma unroll
      for (int mt = 0; mt < 4; ++mt)
        af[mt] = *(const bf16x8*)&Ab[(wm * 128 + mq * 64 + mt * 16 + l15) * 32 + cs * 8];
#pragma unroll
      for (int n = 0; n < 4; ++n)
        bf[n] = *(const bf16x8*)&Bb[(wn * 64 + n * 16 + l15) * 32 + cs * 8];
      // stage schedule: unit (t+1,ks1) at p0/p1; unit (t+2,ks0) at p2/p3.
      // WAR safe: the overwritten region's last readers finished a barrier ago.
      if (p == 0)      { if (t + 1 < nt) stageA(t + 1, 1); }
      else if (p == 1) { if (t + 1 < nt) stageB(t + 1, 1); }
      else if (p == 2) { if (t + 2 < nt) stageA(t + 2, 0); }
      else             { if (t + 2 < nt) stageB(t + 2, 0); }
      __builtin_amdgcn_s_barrier();
      __builtin_amdgcn_s_setprio(1);
#pragma unroll
      for (int mt = 0; mt < 4; ++mt)
#pragma unroll
        for (int n = 0; n < 4; ++n)
          acc[mq][mt][n] = __builtin_amdgcn_mfma_f32_16x16x32_bf16(af[mt], bf[n], acc[mq][mt][n], 0, 0, 0);
      __builtin_amdgcn_s_setprio(0);
      if (p == 3) asm volatile("s_waitcnt vmcnt(4)" ::: "memory");
      __builtin_amdgcn_s_barrier();
    }
  }
  asm volatile("s_waitcnt vmcnt(0)" ::: "memory");
  __builtin_amdgcn_s_barrier();

  // epilogue: wide stores via per-wave LDS region (16 rows x 64 cols per pass)
  OT* Ew = ((OT*)smem) + w * 1024;
#pragma unroll
  for (int mq = 0; mq < 2; ++mq) {
#pragma unroll
    for (int mt = 0; mt < 4; ++mt) {
#pragma unroll
      for (int n = 0; n < 4; ++n)
#pragma unroll
        for (int r = 0; r < 4; ++r)
          ep_set(Ew, (quad * 4 + r) * 64 + n * 16 + l15, acc[mq][mt][n][r]);
      asm volatile("s_waitcnt lgkmcnt(0)" ::: "memory");
#pragma unroll
      for (int it2 = 0; it2 < 4; ++it2) {
        int row_i = it2 * 4 + quad;
        size_t off = (size_t)(m0 + wm * 128 + mq * 64 + mt * 16 + row_i) * ldc + n0 + wn * 64 + l15 * 4;
        if constexpr (sizeof(OT) == 2) {
          *(u16x4*)&C[off] = *(const u16x4*)&Ew[row_i * 64 + l15 * 4];
        } else {
          *(float4*)&C[off] = *(const float4*)&Ew[row_i * 64 + l15 * 4];
        }
      }
      asm volatile("s_waitcnt lgkmcnt(0)" ::: "memory");  // Ew reads done before rewrite
    }
  }
}

// ---------------- GEMM 128x128 (m97-style), kept for the N=64 W_KR GEMM ----------------
template <typename OT>
__global__ __launch_bounds__(256) void gemm_bt(const u16* __restrict__ A, int lda,
                                               const u16* __restrict__ Bt,
                                               OT* __restrict__ C, int ldc,
                                               int M, int N, int K) {
  __shared__ u16 smem_ab[2 * 128 * 32];
  u16* As = smem_ab;
  u16* Bs = smem_ab + 128 * 32;
  const int tid = threadIdx.x;
  const int lane = tid & 63;
  const int w = tid >> 6;
  const int quad = lane >> 4;
  const int l15 = lane & 15;
  const int nwg = gridDim.x * gridDim.y;
  const int lin = blockIdx.y * gridDim.x + blockIdx.x;
  const int swz = (lin & 7) * (nwg >> 3) + (lin >> 3);
  const int m0 = (swz / gridDim.x) * 128;
  const int n0 = (swz % gridDim.x) * 128;
  const int wm = (w & 1) * 64;
  const int wn = (w >> 1) * 64;

  f32x4 acc[4][4] = {};

  for (int k0 = 0; k0 < K; k0 += 32) {
#pragma unroll
    for (int it = 0; it < 2; ++it) {
      int ca = w * 128 + it * 64;
      int c = ca + lane;
      int row = c >> 2, kc = (c & 3) * 8;
      gl_lds16(A + (size_t)(m0 + row) * lda + k0 + kc, &As[ca * 8]);
      gl_lds16(Bt + (size_t)(n0 + row) * K + k0 + kc, &Bs[ca * 8]);
    }
    __syncthreads();
    bf16x8 af[4], bf[4];
#pragma unroll
    for (int mt = 0; mt < 4; ++mt) af[mt] = *(const bf16x8*)&As[(wm + mt * 16 + l15) * 32 + quad * 8];
#pragma unroll
    for (int nt = 0; nt < 4; ++nt) bf[nt] = *(const bf16x8*)&Bs[(wn + nt * 16 + l15) * 32 + quad * 8];
#pragma unroll
    for (int mt = 0; mt < 4; ++mt)
#pragma unroll
      for (int nt = 0; nt < 4; ++nt)
        acc[mt][nt] = __builtin_amdgcn_mfma_f32_16x16x32_bf16(af[mt], bf[nt], acc[mt][nt], 0, 0, 0);
    __syncthreads();
  }

  OT* Ew = ((OT*)smem_ab) + w * 1024;
#pragma unroll
  for (int mt = 0; mt < 4; ++mt) {
#pragma unroll
    for (int nt = 0; nt < 4; ++nt)
#pragma unroll
      for (int r = 0; r < 4; ++r)
        ep_set(Ew, (quad * 4 + r) * 64 + nt * 16 + l15, acc[mt][nt][r]);
    asm volatile("s_waitcnt lgkmcnt(0)" ::: "memory");
#pragma unroll
    for (int it2 = 0; it2 < 4; ++it2) {
      int row_i = it2 * 4 + quad;
      int colg = n0 + wn + l15 * 4;
      if (colg < N) {
        size_t off = (size_t)(m0 + wm + mt * 16 + row_i) * ldc + colg;
        if constexpr (sizeof(OT) == 2) {
          *(u16x4*)&C[off] = *(const u16x4*)&Ew[row_i * 64 + l15 * 4];
        } else {
          *(float4*)&C[off] = *(const float4*)&Ew[row_i * 64 + l15 * 4];
        }
      }
    }
    asm volatile("s_waitcnt lgkmcnt(0)" ::: "memory");
  }
}

// ---------------- build q / k: rope + concat + L2-normalize, one wave per (token, head) ----------------
__global__ __launch_bounds__(256) void build_q(const u16* __restrict__ qcr,  // (B*L, 3072): qc|qr
                                               const float* __restrict__ s_qk,
                                               u16* __restrict__ qn) {
  const int wid = blockIdx.x * 4 + (threadIdx.x >> 6);
  const int lane = threadIdx.x & 63;
  const int token = wid >> 4;     // b*L + l
  const int h = wid & 15;
  const int b = token >> 11;
  const int l = token & 2047;
  float v0 = bf2f(qcr[(size_t)token * 3072 + h * 128 + lane]);
  float v1 = bf2f(qcr[(size_t)token * 3072 + h * 128 + 64 + lane]);
  int j = lane & 31;
  float freq = __expf((float)j * -0.28782313662425574f);   // 10000^(-j/32)
  float ang = (float)l * freq;
  float cs = __cosf(ang), sn = __sinf(ang);
  float xr = bf2f(qcr[(size_t)token * 3072 + 2048 + h * 64 + lane]);
  float xo = bf2f(qcr[(size_t)token * 3072 + 2048 + h * 64 + (lane ^ 32)]);
  float v2 = (lane < 32) ? (xr * cs - xo * sn) : (xr * cs + xo * sn);
  float ss = v0 * v0 + v1 * v1 + v2 * v2;
#pragma unroll
  for (int off = 1; off < 64; off <<= 1) ss += __shfl_xor(ss, off, 64);
  float scale = s_qk[0] / fmaxf(sqrtf(ss), 1e-12f);
  u16* out = qn + (((size_t)(b * 16 + h) * 2048) + l) * 192;
  out[lane] = f2bf(v0 * scale);
  out[64 + lane] = f2bf(v1 * scale);
  out[128 + lane] = f2bf(v2 * scale);
}

__global__ __launch_bounds__(256) void build_k(const u16* __restrict__ kcv,  // (B*L, 4096): kc|v
                                               const u16* __restrict__ krr,  // (B*L, 64)
                                               u16* __restrict__ kn) {
  const int wid = blockIdx.x * 4 + (threadIdx.x >> 6);
  const int lane = threadIdx.x & 63;
  const int token = wid >> 4;
  const int h = wid & 15;
  const int b = token >> 11;
  const int l = token & 2047;
  float v0 = bf2f(kcv[(size_t)token * 4096 + h * 128 + lane]);
  float v1 = bf2f(kcv[(size_t)token * 4096 + h * 128 + 64 + lane]);
  int j = lane & 31;
  float freq = __expf((float)j * -0.28782313662425574f);   // 10000^(-j/32)
  float ang = (float)l * freq;
  float cs = __cosf(ang), sn = __sinf(ang);
  float xr = bf2f(krr[(size_t)token * 64 + lane]);
  float xo = bf2f(krr[(size_t)token * 64 + (lane ^ 32)]);
  float v2 = (lane < 32) ? (xr * cs - xo * sn) : (xr * cs + xo * sn);
  float ss = v0 * v0 + v1 * v1 + v2 * v2;
#pragma unroll
  for (int off = 1; off < 64; off <<= 1) ss += __shfl_xor(ss, off, 64);
  float scale = 1.0f / fmaxf(sqrtf(ss), 1e-12f);
  u16* out = kn + (((size_t)(b * 16 + h) * 2048) + l) * 192;
  out[lane] = f2bf(v0 * scale);
  out[64 + lane] = f2bf(v1 * scale);
  out[128 + lane] = f2bf(v2 * scale);
}

// ---------------- flash attention (causal), 512 thr, balanced pairing ----------------
__global__ __launch_bounds__(512, 2) void flash_attn(const u16* __restrict__ Q,   // (B,H,L,192)
                                                     const u16* __restrict__ Kn,  // (B,H,L,192)
                                                     const u16* __restrict__ Vt,  // (B,H,128,L)
                                                     const float* __restrict__ s_qk,
                                                     u16* __restrict__ O) {       // (B,L,2048)
  constexpr int L = 2048, DQK = 192, DV = 128, KVB = 64;
  constexpr int PSTR = 72;
  __shared__ u16 smem[59392];          // Ks[2][64*192] | Vs[2][128*64] | Ps[8*32*72] = 118784 B
  u16* KsBuf = smem;                   // 2 x 12288 u16
  u16* VsBuf = smem + 24576;           // 2 x 8192 u16
  u16* Ps    = smem + 40960;           // 18432 u16
  const int tid = threadIdx.x;
  const int lane = tid & 63;
  const int w = tid >> 6;       // 0..7, q-row group (32 rows each)
  const int quad = lane >> 4;
  const int l15 = lane & 15;
  const int lin = blockIdx.x;
  const int xcd = lin & 7;
  const int g = lin >> 3;         // 0..31
  const int bh = ((g >> 2) << 3) | xcd;
  const int pairIdx = g & 3;      // qtA = 7-pairIdx, qtB = pairIdx -> 36 tiles each
  const int b = bh >> 4, h = bh & 15;
  const float SMAX = s_qk[0];     // upper bound on every score (unit q,k; q pre-scaled)

  const u16* Kg = Kn + (size_t)bh * L * DQK;
  const u16* Vg = Vt + (size_t)bh * DV * L;

  auto stage = [&](int kt2, int bufi) {
    u16* KsB = KsBuf + bufi * 12288;
    u16* VsB = VsBuf + bufi * 8192;
#pragma unroll
    for (int it = 0; it < 5; ++it) {
      int B0 = it * 512 + w * 64;            // wave-uniform, 64-aligned
      if (B0 < 1536) {
        int p = B0 + lane;
        int r = p / 24, cp = p % 24;
        int c = cp ^ (r & 7);
        gl_lds16(Kg + (size_t)(kt2 * KVB + r) * DQK + c * 8, &KsB[B0 * 8]);
      } else {
        int p = B0 - 1536 + lane;
        int dv = p >> 3, cp = p & 7;
        int c = cp ^ (dv & 7);
        gl_lds16(Vg + (size_t)dv * L + kt2 * KVB + c * 8, &VsB[(B0 - 1536) * 8]);
      }
    }
  };

  bf16x8 ones;
#pragma unroll
  for (int j = 0; j < 8; ++j) ones[j] = (short)0x3F80;   // bf16 1.0

  for (int qp = 0; qp < 2; ++qp) {
    const int qt = (qp == 0) ? (7 - pairIdx) : pairIdx;
    const u16* Qg = Q + ((size_t)bh * L + qt * 256) * DQK;

    bf16x8 qf[2][6];
#pragma unroll
    for (int mt = 0; mt < 2; ++mt)
#pragma unroll
      for (int kd = 0; kd < 6; ++kd)
        qf[mt][kd] = *(const bf16x8*)&Qg[(w * 32 + mt * 16 + l15) * DQK + kd * 32 + quad * 8];

    f32x4 oacc[2][8] = {};
    f32x4 accL[2] = {};           // running row-sum of P via ones-MFMA

    const int nkv = 4 * (qt + 1);   // 64-key tiles
    stage(0, 0);
    __syncthreads();

    for (int kt = 0; kt < nkv; ++kt) {
      const int cur = kt & 1;
      if (kt + 1 < nkv) stage(kt + 1, cur ^ 1);   // prefetch overlaps compute
      const u16* KsC = KsBuf + cur * 12288;
      const u16* VsC = VsBuf + cur * 8192;

      f32x4 s[2][4] = {};
      __builtin_amdgcn_s_setprio(1);
#pragma unroll
      for (int kd = 0; kd < 6; ++kd) {
#pragma unroll
        for (int nt = 0; nt < 4; ++nt) {
          int row = nt * 16 + l15;
          int cp = (kd * 4 + quad) ^ (l15 & 7);
          bf16x8 bb = *(const bf16x8*)&KsC[row * DQK + cp * 8];
#pragma unroll
          for (int mt = 0; mt < 2; ++mt)
            s[mt][nt] = __builtin_amdgcn_mfma_f32_16x16x32_bf16(qf[mt][kd], bb, s[mt][nt], 0, 0, 0);
        }
      }
      __builtin_amdgcn_s_setprio(0);

      const int kcol0 = kt * KVB + l15;
      u16* Pw = &Ps[w * 32 * PSTR];
#pragma unroll
      for (int mt = 0; mt < 2; ++mt) {
        const int qrow_base = qt * 256 + w * 32 + mt * 16 + quad * 4;
#pragma unroll
        for (int r = 0; r < 4; ++r)
#pragma unroll
          for (int nt = 0; nt < 4; ++nt) {
            float p = (kcol0 + nt * 16 > qrow_base + r) ? 0.f : __expf(s[mt][nt][r] - SMAX);
            Pw[(mt * 16 + quad * 4 + r) * PSTR + nt * 16 + l15] = f2bf(p);
          }
      }
      asm volatile("s_waitcnt lgkmcnt(0)" ::: "memory");

      __builtin_amdgcn_s_setprio(1);
      bf16x8 pf[2][2];
#pragma unroll
      for (int mt = 0; mt < 2; ++mt)
#pragma unroll
        for (int kc = 0; kc < 2; ++kc) {
          pf[mt][kc] = *(const bf16x8*)&Pw[(mt * 16 + l15) * PSTR + kc * 32 + quad * 8];
          accL[mt] = __builtin_amdgcn_mfma_f32_16x16x32_bf16(pf[mt][kc], ones, accL[mt], 0, 0, 0);
        }
#pragma unroll
      for (int nt2 = 0; nt2 < 8; ++nt2) {
        const int dv = nt2 * 16 + l15;
#pragma unroll
        for (int kc = 0; kc < 2; ++kc) {
          int lc = (kc * 4 + quad) ^ (l15 & 7);   // dv&7 == l15&7
          bf16x8 vv = *(const bf16x8*)&VsC[dv * KVB + lc * 8];
#pragma unroll
          for (int mt = 0; mt < 2; ++mt)
            oacc[mt][nt2] = __builtin_amdgcn_mfma_f32_16x16x32_bf16(pf[mt][kc], vv, oacc[mt][nt2], 0, 0, 0);
        }
      }
      __builtin_amdgcn_s_setprio(0);
      __syncthreads();  // drains prefetch (vmcnt) + frees cur buffer
    }

    float rinv[2][4];
#pragma unroll
    for (int mt = 0; mt < 2; ++mt)
#pragma unroll
      for (int r = 0; r < 4; ++r) rinv[mt][r] = 1.0f / accL[mt][r];
    u16* Ew = smem + w * 2048;
#pragma unroll
    for (int mt = 0; mt < 2; ++mt) {
#pragma unroll
      for (int nt2 = 0; nt2 < 8; ++nt2)
#pragma unroll
        for (int r = 0; r < 4; ++r)
          Ew[(quad * 4 + r) * 128 + nt2 * 16 + l15] = f2bf(oacc[mt][nt2][r] * rinv[mt][r]);
      asm volatile("s_waitcnt lgkmcnt(0)" ::: "memory");
#pragma unroll
      for (int it2 = 0; it2 < 4; ++it2) {
        int row_i = it2 * 4 + quad;
        int lg = qt * 256 + w * 32 + mt * 16 + row_i;
        uint4 v = *(const uint4*)&Ew[row_i * 128 + l15 * 8];
        *(uint4*)&O[((size_t)b * L + lg) * 2048 + h * 128 + l15 * 8] = v;
      }
      asm volatile("s_waitcnt lgkmcnt(0)" ::: "memory");
    }
    __syncthreads();   // protect Ew region before next pass's stage(0,0)
  }
}

// ---------------- launcher ----------------
extern "C" void kernel_launch(void* const* d_in, const int* in_sizes, int n_in,
                              void* d_out, int out_size, void* d_ws, size_t ws_size,
                              hipStream_t stream) {
  const float* x     = (const float*)d_in[0];
  const float* W_DKV = (const float*)d_in[1];
  const float* W_UK  = (const float*)d_in[2];
  const float* W_UV  = (const float*)d_in[3];
  const float* W_DQ  = (const float*)d_in[4];
  const float* W_UQ  = (const float*)d_in[5];
  const float* W_QR  = (const float*)d_in[6];
  const float* W_KR  = (const float*)d_in[7];
  const float* W_O   = (const float*)d_in[8];
  const float* s_qk  = (const float*)d_in[9];

  char* base = (char*)d_ws;
  // static layout (bytes) — high-water mark 232,259,584 B (221.5 MiB):
  u16* xb     = (u16*)(base);                        // [0, 33,554,432)           dead after G_KR
  u16* WtDKVQ = (u16*)(base + (size_t)33554432);     // [.., 41,943,040)  8.39 MB dead after G1
  u16* WtUKV  = (u16*)(base + (size_t)41943040);     // [.., 58,720,256) 16.78 MB dead after G2
  u16* WtUQR  = (u16*)(base + (size_t)58720256);     // [.., 71,303,168) 12.58 MB dead after G3
  u16* WtKR   = (u16*)(base + (size_t)71303168);     // [.., 71,827,456)  0.52 MB dead after G_KR
  u16* WtO    = (u16*)(base + (size_t)71827456);     // [.., 80,216,064)  8.39 MB live to end
  u16* ckvq   = (u16*)(base + (size_t)80216064);     // [.., 113,770,496) 33.55 MB dead after G3
  u16* kcv    = (u16*)(base + (size_t)113770496);    // [.., 180,879,360) 67.11 MB dead after transpose_v
  u16* qcr    = (u16*)(base + (size_t)180879360);    // [.., 231,211,008) 50.33 MB dead after build_q
  u16* kr     = (u16*)(base + (size_t)231211008);    // [.., 232,259,584)  1.05 MB
  // aliases (each writer runs strictly after the aliased region's last reader):
  u16* qn = (u16*)(base);      // 50.33 MB over xb+WtDKVQ+WtUKV (all dead before build_q)
  u16* kn = qcr;               // 50.33 MB, exact size match; build_k runs after build_q
  u16* Vt = ckvq;              // 33.55 MB over ckvq (dead after G3)
  u16* O  = kcv;               // 33.55 MB over kcv head (dead after transpose_v)

  // 1) casts / weight transposes (into merged layouts)
  cast_f32_bf16<<<16384, 256, 0, stream>>>(x, xb, 8192 * 2048 / 4);
  transpose_cast<<<dim3(16, 32), 256, 0, stream>>>(W_DKV, WtDKVQ,                  2048, 1024);
  transpose_cast<<<dim3(16, 32), 256, 0, stream>>>(W_DQ,  WtDKVQ + 1024 * 2048,    2048, 1024);
  transpose_cast<<<dim3(32, 16), 256, 0, stream>>>(W_UK,  WtUKV,                   1024, 2048);
  transpose_cast<<<dim3(32, 16), 256, 0, stream>>>(W_UV,  WtUKV + 2048 * 1024,     1024, 2048);
  transpose_cast<<<dim3(32, 16), 256, 0, stream>>>(W_UQ,  WtUQR,                   1024, 2048);
  transpose_cast<<<dim3(16, 16), 256, 0, stream>>>(W_QR,  WtUQR + 2048 * 1024,     1024, 1024);
  transpose_cast<<<dim3(1, 32),  256, 0, stream>>>(W_KR,  WtKR,                    2048, 64);
  transpose_cast<<<dim3(32, 32), 256, 0, stream>>>(W_O,   WtO,                     2048, 2048);

  // 2) merged projection GEMMs (256x256 8-phase for the big four)
  gemm256<u16><<<dim3(8, 32),  512, 0, stream>>>(xb, 2048, WtDKVQ, ckvq, 2048, 2048);
  gemm_bt<u16><<<dim3(1, 64),  256, 0, stream>>>(xb, 2048, WtKR, kr, 64, 8192, 64, 2048);
  gemm256<u16><<<dim3(16, 32), 512, 0, stream>>>(ckvq, 2048, WtUKV, kcv, 4096, 1024);
  gemm256<u16><<<dim3(12, 32), 512, 0, stream>>>(ckvq + 1024, 2048, WtUQR, qcr, 3072, 1024);

  // 3) rope + concat + normalize (build_q consumes qcr, THEN build_k writes kn over it)
  build_q<<<32768, 256, 0, stream>>>(qcr, s_qk, qn);
  build_k<<<32768, 256, 0, stream>>>(kcv, kr, kn);

  // 4) V transpose (Vt over dead ckvq region)
  transpose_v<<<dim3(32, 2, 64), 256, 0, stream>>>(kcv, Vt);

  // 5) attention: 256 blocks x 512 thr, balanced q-tile pairs, 64-key tiles
  flash_attn<<<dim3(256), 512, 0, stream>>>(qn, kn, Vt, s_qk, O);

  // 6) output projection -> fp32 d_out
  gemm256<float><<<dim3(8, 32), 512, 0, stream>>>(O, 2048, WtO, (float*)d_out, 2048, 2048);
}

// Round 4
// 623.063 us; speedup vs baseline: 2.0429x; 1.0885x over previous
//
#include <hip/hip_runtime.h>
#include <stdint.h>

typedef unsigned short u16;
typedef unsigned int u32;
typedef short bf16x8 __attribute__((ext_vector_type(8)));
typedef float f32x4 __attribute__((ext_vector_type(4)));
typedef u16 u16x4 __attribute__((ext_vector_type(4)));

#define DEV __device__ __forceinline__

DEV float bf2f(u16 u) { union { float f; u32 i; } x; x.i = ((u32)u) << 16; return x.f; }
DEV u16 f2bf(float f) {
  union { float f; u32 i; } x; x.f = f;
  u32 i = x.i;
  u32 r = (i + 0x7fffu + ((i >> 16) & 1u)) >> 16;  // RTNE
  return (u16)r;
}

// async global->LDS, 16B per lane. lds base must be wave-uniform; HW adds lane*16.
DEV void gl_lds16(const u16* g, u16* l) {
  __builtin_amdgcn_global_load_lds((const __attribute__((address_space(1))) u32*)g,
                                   (__attribute__((address_space(3))) u32*)l, 16, 0, 0);
}

// ---------------- prep: x cast + all weight transposes + pad zero, ONE launch ----------------
// block ranges: [0,4096) cast x; then 8 transposes; then zero-pad of WtDKVQpad rows 2112..2303.
__global__ __launch_bounds__(256) void prep(const float* __restrict__ x,
                                            const float* __restrict__ W_DKV,
                                            const float* __restrict__ W_UK,
                                            const float* __restrict__ W_UV,
                                            const float* __restrict__ W_DQ,
                                            const float* __restrict__ W_UQ,
                                            const float* __restrict__ W_QR,
                                            const float* __restrict__ W_KR,
                                            const float* __restrict__ W_O,
                                            u16* __restrict__ xb,
                                            u16* __restrict__ WtDKVQ,   // 2304 x 2048 (rows 2048..2111 = KR^T, 2112..2303 = 0)
                                            u16* __restrict__ WtUKV,    // 7168 x 1024 (UK|UV|UQ|QR stacked)
                                            u16* __restrict__ WtO) {
  __shared__ float tile[64][65];
  const int tid = threadIdx.x;
  int bid = blockIdx.x;

  if (bid < 4096) {   // cast x -> bf16, 4 float4 per thread
#pragma unroll
    for (int it = 0; it < 4; ++it) {
      int i = bid * 1024 + it * 256 + tid;
      float4 v = ((const float4*)x)[i];
      u16x4 o;
      o.x = f2bf(v.x); o.y = f2bf(v.y); o.z = f2bf(v.z); o.w = f2bf(v.w);
      ((u16x4*)xb)[i] = o;
    }
    return;
  }
  bid -= 4096;

  const float* W; u16* Wt; int K, N;
  if (bid < 512)        { W = W_DKV; Wt = WtDKVQ;                K = 2048; N = 1024; }
  else if (bid < 1024)  { W = W_DQ;  Wt = WtDKVQ + 1024 * 2048;  K = 2048; N = 1024; bid -= 512; }
  else if (bid < 1536)  { W = W_UK;  Wt = WtUKV;                 K = 1024; N = 2048; bid -= 1024; }
  else if (bid < 2048)  { W = W_UV;  Wt = WtUKV + 2048 * 1024;   K = 1024; N = 2048; bid -= 1536; }
  else if (bid < 2560)  { W = W_UQ;  Wt = WtUKV + 4096 * 1024;   K = 1024; N = 2048; bid -= 2048; }
  else if (bid < 2816)  { W = W_QR;  Wt = WtUKV + 6144 * 1024;   K = 1024; N = 1024; bid -= 2560; }
  else if (bid < 2848)  { W = W_KR;  Wt = WtDKVQ + 2048 * 2048;  K = 2048; N = 64;   bid -= 2816; }
  else if (bid < 3040) {  // zero pad rows 2112..2303 of WtDKVQpad
    int i = (bid - 2848) * 256 + tid;
    *(uint4*)&WtDKVQ[2112 * 2048 + i * 8] = uint4{0, 0, 0, 0};
    return;
  }
  else                  { W = W_O;   Wt = WtO;                   K = 2048; N = 2048; bid -= 3040; }

  const int gx = N >> 6;
  const int n0 = (bid % gx) * 64;
  const int k0 = (bid / gx) * 64;
#pragma unroll
  for (int i = 0; i < 16; ++i) {
    int idx = tid + i * 256;
    int r = idx >> 6, c = idx & 63;             // r: k-off, c: n-off
    tile[r][c] = W[(size_t)(k0 + r) * N + n0 + c];
  }
  __syncthreads();
#pragma unroll
  for (int i = 0; i < 16; ++i) {
    int idx = tid + i * 256;
    int r = idx >> 6, c = idx & 63;             // r: n-off, c: k-off
    Wt[(size_t)(n0 + r) * K + k0 + c] = f2bf(tile[c][r]);
  }
}

DEV void ep_set(u16* E, int i, float v) { E[i] = f2bf(v); }
DEV void ep_set(float* E, int i, float v) { E[i] = v; }

// ---------------- GEMM 256x256 8-phase (T2+T3+T4+T5): C = A(MxK) * Bt(NxK)^T ----------------
// KIND 0: plain C.  KIND 1 (G1+KR): n0==2048 -> store only cols<64 into X1 (kr, ldc 64).
// KIND 2 (G2+G3 merged): n0<2048 -> C=kc ldc2048; 2048<=n0<4096 -> X1=Vt TRANSPOSED write;
//                        n0>=4096 -> X2=qcr ldc3072, A offset +1024.
// Counted vmcnt(4) once per K-tile, raw s_barrier, read-side XOR swizzle with
// pre-swizzled global source (both-sides rule), setprio around MFMA.
template <typename OT, int KIND>
__global__ __launch_bounds__(512, 2) void gemm256(const u16* __restrict__ A, int lda,
                                                  const u16* __restrict__ Bt,
                                                  OT* __restrict__ C, int ldc, int K,
                                                  u16* __restrict__ X1, u16* __restrict__ X2) {
  __shared__ u16 smem[65536];   // 128KB: buf[t&1]{ A[2][256][32] | B[2][256][32] }
  const int tid = threadIdx.x;
  const int lane = tid & 63;
  const int w = tid >> 6;       // 0..7
  const int wm = w >> 2;        // 0..1 (M)
  const int wn = w & 3;         // 0..3 (N)
  const int quad = lane >> 4;
  const int l15 = lane & 15;
  const int cs = quad ^ ((l15 >> 1) & 3);   // swizzled k-chunk for frag reads
  // T1 bijective XCD swizzle (nwg % 8 == 0 for all our grids)
  const int nwg = gridDim.x * gridDim.y;
  const int lin = blockIdx.y * gridDim.x + blockIdx.x;
  const int swz = (lin & 7) * (nwg >> 3) + (lin >> 3);
  const int m0 = (swz / gridDim.x) * 256;
  const int n0 = (swz % gridDim.x) * 256;

  // staging per-thread geometry: thread covers row rloc, phys chunk tid&3;
  // pre-swizzled source column so linear LDS dest + swizzled read match.
  const int rloc = tid >> 2;                       // 0..127
  const int clog = (tid & 3) ^ ((tid >> 3) & 3);   // pre-swizzled source column
  const u16* Abase = A + ((KIND == 2 && n0 >= 4096) ? 1024 : 0);
  const size_t aoff0 = (size_t)rloc * lda + clog * 8;
  const size_t boff0 = (size_t)rloc * (size_t)K + clog * 8;
  const u16* Ag = Abase + (size_t)m0 * lda;
  const u16* Bg = Bt + (size_t)n0 * K;

  auto stageA = [&](int u, int ks2) {
    u16* dst = smem + (u & 1) * 32768 + ks2 * 8192 + w * 512;
    const u16* s0 = Ag + aoff0 + u * 64 + ks2 * 32;
    gl_lds16(s0, dst);
    gl_lds16(s0 + (size_t)128 * lda, dst + 4096);
  };
  auto stageB = [&](int u, int ks2) {
    u16* dst = smem + (u & 1) * 32768 + 16384 + ks2 * 8192 + w * 512;
    const u16* s0 = Bg + boff0 + u * 64 + ks2 * 32;
    gl_lds16(s0, dst);
    gl_lds16(s0 + (size_t)128 * (size_t)K, dst + 4096);
  };

  f32x4 acc[2][4][4] = {};   // [mq][mt][n], all indices compile-time
  const int nt = K >> 6;

  stageA(0, 0); stageB(0, 0); stageA(0, 1); stageB(0, 1);
  stageA(1, 0); stageB(1, 0);
  asm volatile("s_waitcnt vmcnt(4)" ::: "memory");
  __builtin_amdgcn_s_barrier();

  for (int t = 0; t < nt; ++t) {
    const u16* As_ = smem + (t & 1) * 32768;
    const u16* Bs_ = As_ + 16384;
#pragma unroll
    for (int p = 0; p < 4; ++p) {
      const int ks = p >> 1;
      const int mq = p & 1;
      const u16* Ab = As_ + ks * 8192;
      const u16* Bb = Bs_ + ks * 8192;
      bf16x8 af[4], bf[4];
#pragma unroll
      for (int mt = 0; mt < 4; ++mt)
        af[mt] = *(const bf16x8*)&Ab[(wm * 128 + mq * 64 + mt * 16 + l15) * 32 + cs * 8];
#pragma unroll
      for (int n = 0; n < 4; ++n)
        bf[n] = *(const bf16x8*)&Bb[(wn * 64 + n * 16 + l15) * 32 + cs * 8];
      if (p == 0)      { if (t + 1 < nt) stageA(t + 1, 1); }
      else if (p == 1) { if (t + 1 < nt) stageB(t + 1, 1); }
      else if (p == 2) { if (t + 2 < nt) stageA(t + 2, 0); }
      else             { if (t + 2 < nt) stageB(t + 2, 0); }
      __builtin_amdgcn_s_barrier();
      __builtin_amdgcn_s_setprio(1);
#pragma unroll
      for (int mt = 0; mt < 4; ++mt)
#pragma unroll
        for (int n = 0; n < 4; ++n)
          acc[mq][mt][n] = __builtin_amdgcn_mfma_f32_16x16x32_bf16(af[mt], bf[n], acc[mq][mt][n], 0, 0, 0);
      __builtin_amdgcn_s_setprio(0);
      if (p == 3) asm volatile("s_waitcnt vmcnt(4)" ::: "memory");
      __builtin_amdgcn_s_barrier();
    }
  }
  asm volatile("s_waitcnt vmcnt(0)" ::: "memory");
  __builtin_amdgcn_s_barrier();

  if constexpr (KIND == 2) {
    if (n0 >= 2048 && n0 < 4096) {
      // VMODE: write this quadrant transposed into Vt (b,h,dv,L).
      // Per (mq,mh) pass: 64 dv-cols x 32 tokens via LDS (stride 40 u16 to spread banks),
      // then each lane stores one dv column = 64B contiguous in L.
      u16* Ewt = smem + w * 2560;        // 64 * 40 u16 = 5120B per wave
      const int dvb = (n0 - 2048) + wn * 64;
      const int hh = dvb >> 7;
      const int dv0 = dvb & 127;         // 0 or 64
#pragma unroll
      for (int mq = 0; mq < 2; ++mq)
#pragma unroll
        for (int mh = 0; mh < 2; ++mh) {
#pragma unroll
          for (int mi = 0; mi < 2; ++mi)
#pragma unroll
            for (int n = 0; n < 4; ++n)
#pragma unroll
              for (int r = 0; r < 4; ++r)
                Ewt[(n * 16 + l15) * 40 + mi * 16 + quad * 4 + r] = f2bf(acc[mq][mh * 2 + mi][n][r]);
          asm volatile("s_waitcnt lgkmcnt(0)" ::: "memory");
          const int mbase = m0 + wm * 128 + mq * 64 + mh * 32;
          const int b_ = mbase >> 11, l_ = mbase & 2047;
          u16* dstp = X1 + ((size_t)((b_ * 16 + hh) * 128 + dv0 + lane)) * 2048 + l_;
          const u16* srcp = &Ewt[lane * 40];
#pragma unroll
          for (int k2 = 0; k2 < 4; ++k2)
            *(uint4*)&dstp[k2 * 8] = *(const uint4*)&srcp[k2 * 8];
          asm volatile("s_waitcnt lgkmcnt(0)" ::: "memory");
        }
      return;
    }
  }

  // normal epilogue: wide stores via per-wave LDS region (16 rows x 64 cols per pass)
  OT* Cc = C; int ldcc = ldc, col0 = n0, Nlim = 1 << 30;
  if constexpr (KIND == 1) {
    if (n0 == 2048) { Cc = (OT*)X1; ldcc = 64; col0 = 0; Nlim = 64; }
  }
  if constexpr (KIND == 2) {
    if (n0 >= 4096) { Cc = (OT*)X2; ldcc = 3072; col0 = n0 - 4096; }
  }
  OT* Ew = ((OT*)smem) + w * 1024;
#pragma unroll
  for (int mq = 0; mq < 2; ++mq) {
#pragma unroll
    for (int mt = 0; mt < 4; ++mt) {
#pragma unroll
      for (int n = 0; n < 4; ++n)
#pragma unroll
        for (int r = 0; r < 4; ++r)
          ep_set(Ew, (quad * 4 + r) * 64 + n * 16 + l15, acc[mq][mt][n][r]);
      asm volatile("s_waitcnt lgkmcnt(0)" ::: "memory");
#pragma unroll
      for (int it2 = 0; it2 < 4; ++it2) {
        int row_i = it2 * 4 + quad;
        int colg = wn * 64 + l15 * 4;
        if (colg < Nlim) {
          size_t off = (size_t)(m0 + wm * 128 + mq * 64 + mt * 16 + row_i) * ldcc + col0 + colg;
          if constexpr (sizeof(OT) == 2) {
            *(u16x4*)&Cc[off] = *(const u16x4*)&Ew[row_i * 64 + l15 * 4];
          } else {
            *(float4*)&Cc[off] = *(const float4*)&Ew[row_i * 64 + l15 * 4];
          }
        }
      }
      asm volatile("s_waitcnt lgkmcnt(0)" ::: "memory");
    }
  }
}

// ---------------- build k: rope + concat + L2-normalize, one wave per (token, head) ----------------
__global__ __launch_bounds__(256) void build_k(const u16* __restrict__ kc,   // (B*L, 2048)
                                               const u16* __restrict__ krr,  // (B*L, 64)
                                               u16* __restrict__ kn) {
  const int wid = blockIdx.x * 4 + (threadIdx.x >> 6);
  const int lane = threadIdx.x & 63;
  const int token = wid >> 4;
  const int h = wid & 15;
  const int b = token >> 11;
  const int l = token & 2047;
  float v0 = bf2f(kc[(size_t)token * 2048 + h * 128 + lane]);
  float v1 = bf2f(kc[(size_t)token * 2048 + h * 128 + 64 + lane]);
  int j = lane & 31;
  float freq = __expf((float)j * -0.28782313662425574f);   // 10000^(-j/32)
  float ang = (float)l * freq;
  float cs = __cosf(ang), sn = __sinf(ang);
  float xr = bf2f(krr[(size_t)token * 64 + lane]);
  float xo = bf2f(krr[(size_t)token * 64 + (lane ^ 32)]);
  float v2 = (lane < 32) ? (xr * cs - xo * sn) : (xr * cs + xo * sn);
  float ss = v0 * v0 + v1 * v1 + v2 * v2;
#pragma unroll
  for (int off = 1; off < 64; off <<= 1) ss += __shfl_xor(ss, off, 64);
  float scale = 1.0f / fmaxf(sqrtf(ss), 1e-12f);
  u16* out = kn + (((size_t)(b * 16 + h) * 2048) + l) * 192;
  out[lane] = f2bf(v0 * scale);
  out[64 + lane] = f2bf(v1 * scale);
  out[128 + lane] = f2bf(v2 * scale);
}

// ---------------- flash attention (causal), 512 thr, balanced pairing, fused Q-build ----------------
// Q rope+normalize done in-register from qcr: rope pairs (j, j+32) live at the same
// element position of the kd4/kd5 fragments (lane-local); row L2-norm = 2 shfl_xor
// over quads. Static-max softmax (scores <= s_qk); denominator via ones-MFMA.
__global__ __launch_bounds__(512, 2) void flash_attn(const u16* __restrict__ qcr, // (B*L, 3072): qc|qr
                                                     const u16* __restrict__ Kn,  // (B,H,L,192)
                                                     const u16* __restrict__ Vt,  // (B,H,128,L)
                                                     const float* __restrict__ s_qk,
                                                     u16* __restrict__ O) {       // (B,L,2048)
  constexpr int L = 2048, DQK = 192, DV = 128, KVB = 64;
  constexpr int PSTR = 72;
  __shared__ u16 smem[59392];          // Ks[2][64*192] | Vs[2][128*64] | Ps[8*32*72] = 118784 B
  u16* KsBuf = smem;                   // 2 x 12288 u16
  u16* VsBuf = smem + 24576;           // 2 x 8192 u16
  u16* Ps    = smem + 40960;           // 18432 u16
  const int tid = threadIdx.x;
  const int lane = tid & 63;
  const int w = tid >> 6;       // 0..7, q-row group (32 rows each)
  const int quad = lane >> 4;
  const int l15 = lane & 15;
  const int lin = blockIdx.x;
  const int xcd = lin & 7;
  const int g = lin >> 3;         // 0..31
  const int bh = ((g >> 2) << 3) | xcd;
  const int pairIdx = g & 3;      // qtA = 7-pairIdx, qtB = pairIdx -> 36 tiles each
  const int b = bh >> 4, h = bh & 15;
  const float SMAX = s_qk[0];     // upper bound on every score (unit q,k; q pre-scaled)

  const u16* Kg = Kn + (size_t)bh * L * DQK;
  const u16* Vg = Vt + (size_t)bh * DV * L;

  // stage address precompute (constant across kt): K 1536 chunks, V 1024 chunks,
  // both column-XOR-pre-swizzled on the global side, linear LDS dest.
  int koffs[3], kdsts[3], voffs[2], vdsts[2];
#pragma unroll
  for (int it = 0; it < 3; ++it) {
    int p = it * 512 + w * 64 + lane;
    int r = p / 24, cp = p % 24;
    koffs[it] = r * DQK + (cp ^ (r & 7)) * 8;
    kdsts[it] = (it * 512 + w * 64) * 8;
  }
#pragma unroll
  for (int it = 0; it < 2; ++it) {
    int q = (it + 3) * 512 + w * 64 + lane - 1536;
    int dv = q >> 3, cp = q & 7;
    voffs[it] = dv * L + (cp ^ (dv & 7)) * 8;
    vdsts[it] = ((it + 3) * 512 + w * 64 - 1536) * 8;
  }

  auto stage = [&](int kt2, int bufi) {
    u16* KsB = KsBuf + bufi * 12288;
    u16* VsB = VsBuf + bufi * 8192;
    const u16* Kt = Kg + (size_t)(kt2 * KVB) * DQK;
    const u16* Vtb = Vg + kt2 * KVB;
#pragma unroll
    for (int it = 0; it < 3; ++it) gl_lds16(Kt + koffs[it], &KsB[kdsts[it]]);
#pragma unroll
    for (int it = 0; it < 2; ++it) gl_lds16(Vtb + voffs[it], &VsB[vdsts[it]]);
  };

  bf16x8 ones;
#pragma unroll
  for (int j = 0; j < 8; ++j) ones[j] = (short)0x3F80;   // bf16 1.0

  for (int qp = 0; qp < 2; ++qp) {
    const int qt = (qp == 0) ? (7 - pairIdx) : pairIdx;

    // ---- fused Q-build: load raw qc|qr, rope kd4/5, L2-normalize, scale by s_qk ----
    bf16x8 qf[2][6];
#pragma unroll
    for (int mt = 0; mt < 2; ++mt) {
      const int row = qt * 256 + w * 32 + mt * 16 + l15;
      const u16* qr_ = qcr + (size_t)(b * 2048 + row) * 3072;
#pragma unroll
      for (int kd = 0; kd < 4; ++kd)
        qf[mt][kd] = *(const bf16x8*)&qr_[h * 128 + kd * 32 + quad * 8];
      bf16x8 a4 = *(const bf16x8*)&qr_[2048 + h * 64 + quad * 8];
      bf16x8 a5 = *(const bf16x8*)&qr_[2048 + h * 64 + 32 + quad * 8];
      float v4[8], v5[8];
      float ss = 0.f;
#pragma unroll
      for (int e = 0; e < 8; ++e) {
        int j = quad * 8 + e;
        float fr = __expf((float)j * -0.28782313662425574f);
        float ang = (float)row * fr;
        float cs2 = __cosf(ang), sn2 = __sinf(ang);
        float x4 = bf2f((u16)a4[e]), x5 = bf2f((u16)a5[e]);
        v4[e] = x4 * cs2 - x5 * sn2;
        v5[e] = x5 * cs2 + x4 * sn2;
        ss += v4[e] * v4[e] + v5[e] * v5[e];
      }
#pragma unroll
      for (int kd = 0; kd < 4; ++kd)
#pragma unroll
        for (int e = 0; e < 8; ++e) { float xv = bf2f((u16)qf[mt][kd][e]); ss += xv * xv; }
      ss += __shfl_xor(ss, 16, 64);
      ss += __shfl_xor(ss, 32, 64);
      float scale = SMAX / fmaxf(sqrtf(ss), 1e-12f);
#pragma unroll
      for (int kd = 0; kd < 4; ++kd) {
        bf16x8 t = qf[mt][kd];
#pragma unroll
        for (int e = 0; e < 8; ++e) t[e] = (short)f2bf(bf2f((u16)t[e]) * scale);
        qf[mt][kd] = t;
      }
      bf16x8 t4, t5;
#pragma unroll
      for (int e = 0; e < 8; ++e) { t4[e] = (short)f2bf(v4[e] * scale); t5[e] = (short)f2bf(v5[e] * scale); }
      qf[mt][4] = t4; qf[mt][5] = t5;
    }

    f32x4 oacc[2][8] = {};
    f32x4 accL[2] = {};           // running row-sum of P via ones-MFMA

    const int nkv = 4 * (qt + 1);   // 64-key tiles
    stage(0, 0);
    __syncthreads();

    for (int kt = 0; kt < nkv; ++kt) {
      const int cur = kt & 1;
      if (kt + 1 < nkv) stage(kt + 1, cur ^ 1);   // prefetch overlaps compute
      const u16* KsC = KsBuf + cur * 12288;
      const u16* VsC = VsBuf + cur * 8192;

      f32x4 s[2][4] = {};
      __builtin_amdgcn_s_setprio(1);
#pragma unroll
      for (int kd = 0; kd < 6; ++kd) {
#pragma unroll
        for (int nt = 0; nt < 4; ++nt) {
          int row = nt * 16 + l15;
          int cp = (kd * 4 + quad) ^ (l15 & 7);
          bf16x8 bb = *(const bf16x8*)&KsC[row * DQK + cp * 8];
#pragma unroll
          for (int mt = 0; mt < 2; ++mt)
            s[mt][nt] = __builtin_amdgcn_mfma_f32_16x16x32_bf16(qf[mt][kd], bb, s[mt][nt], 0, 0, 0);
        }
      }
      __builtin_amdgcn_s_setprio(0);

      const int kcol0 = kt * KVB + l15;
      u16* Pw = &Ps[w * 32 * PSTR];
#pragma unroll
      for (int mt = 0; mt < 2; ++mt) {
        const int qrow_base = qt * 256 + w * 32 + mt * 16 + quad * 4;
#pragma unroll
        for (int r = 0; r < 4; ++r)
#pragma unroll
          for (int nt = 0; nt < 4; ++nt) {
            float p = (kcol0 + nt * 16 > qrow_base + r) ? 0.f : __expf(s[mt][nt][r] - SMAX);
            Pw[(mt * 16 + quad * 4 + r) * PSTR + nt * 16 + l15] = f2bf(p);
          }
      }
      asm volatile("s_waitcnt lgkmcnt(0)" ::: "memory");

      __builtin_amdgcn_s_setprio(1);
      bf16x8 pf[2][2];
#pragma unroll
      for (int mt = 0; mt < 2; ++mt)
#pragma unroll
        for (int kc2 = 0; kc2 < 2; ++kc2) {
          pf[mt][kc2] = *(const bf16x8*)&Pw[(mt * 16 + l15) * PSTR + kc2 * 32 + quad * 8];
          accL[mt] = __builtin_amdgcn_mfma_f32_16x16x32_bf16(pf[mt][kc2], ones, accL[mt], 0, 0, 0);
        }
#pragma unroll
      for (int nt2 = 0; nt2 < 8; ++nt2) {
        const int dv = nt2 * 16 + l15;
#pragma unroll
        for (int kc2 = 0; kc2 < 2; ++kc2) {
          int lc = (kc2 * 4 + quad) ^ (l15 & 7);   // dv&7 == l15&7
          bf16x8 vv = *(const bf16x8*)&VsC[dv * KVB + lc * 8];
#pragma unroll
          for (int mt = 0; mt < 2; ++mt)
            oacc[mt][nt2] = __builtin_amdgcn_mfma_f32_16x16x32_bf16(pf[mt][kc2], vv, oacc[mt][nt2], 0, 0, 0);
        }
      }
      __builtin_amdgcn_s_setprio(0);
      __syncthreads();  // drains prefetch (vmcnt) + frees cur buffer
    }

    float rinv[2][4];
#pragma unroll
    for (int mt = 0; mt < 2; ++mt)
#pragma unroll
      for (int r = 0; r < 4; ++r) rinv[mt][r] = 1.0f / accL[mt][r];
    u16* Ew = smem + w * 2048;
#pragma unroll
    for (int mt = 0; mt < 2; ++mt) {
#pragma unroll
      for (int nt2 = 0; nt2 < 8; ++nt2)
#pragma unroll
        for (int r = 0; r < 4; ++r)
          Ew[(quad * 4 + r) * 128 + nt2 * 16 + l15] = f2bf(oacc[mt][nt2][r] * rinv[mt][r]);
      asm volatile("s_waitcnt lgkmcnt(0)" ::: "memory");
#pragma unroll
      for (int it2 = 0; it2 < 4; ++it2) {
        int row_i = it2 * 4 + quad;
        int lg = qt * 256 + w * 32 + mt * 16 + row_i;
        uint4 v = *(const uint4*)&Ew[row_i * 128 + l15 * 8];
        *(uint4*)&O[((size_t)b * L + lg) * 2048 + h * 128 + l15 * 8] = v;
      }
      asm volatile("s_waitcnt lgkmcnt(0)" ::: "memory");
    }
    __syncthreads();   // protect Ew region before next pass's stage(0,0)
  }
}

// ---------------- launcher ----------------
extern "C" void kernel_launch(void* const* d_in, const int* in_sizes, int n_in,
                              void* d_out, int out_size, void* d_ws, size_t ws_size,
                              hipStream_t stream) {
  const float* x     = (const float*)d_in[0];
  const float* W_DKV = (const float*)d_in[1];
  const float* W_UK  = (const float*)d_in[2];
  const float* W_UV  = (const float*)d_in[3];
  const float* W_DQ  = (const float*)d_in[4];
  const float* W_UQ  = (const float*)d_in[5];
  const float* W_QR  = (const float*)d_in[6];
  const float* W_KR  = (const float*)d_in[7];
  const float* W_O   = (const float*)d_in[8];
  const float* s_qk  = (const float*)d_in[9];

  char* base = (char*)d_ws;
  // static layout (bytes) — high-water 218,103,808 B (208 MiB):
  u16* xb     = (u16*)(base);                        // [0, 32M)        dead after G1
  u16* WtDKVQ = (u16*)(base + (size_t)33554432);     // [32M, 41M)  2304x2048 (DKV|DQ|KR|pad0), dead after G1
  u16* WtUKV  = (u16*)(base + (size_t)42991616);     // [41M, 55M)  7168x1024 (UK|UV|UQ|QR), dead after G23
  u16* WtO    = (u16*)(base + (size_t)57671680);     // [55M, 63M)  live to end
  u16* ckvq   = (u16*)(base + (size_t)66060288);     // [63M, 95M)  written G1, read G23, dead after
  u16* kc     = (u16*)(base + (size_t)99614720);     // [95M, 127M) written G23, read build_k
  u16* Vt     = (u16*)(base + (size_t)133169152);    // [127M,159M) written G23 (VMODE), read flash
  u16* qcr    = (u16*)(base + (size_t)166723584);    // [159M,207M) written G23, read flash (fused Q)
  u16* kr     = (u16*)(base + (size_t)217055232);    // [207M,208M) written G1 (KR cols), read build_k
  // aliases:
  u16* kn = (u16*)(base);      // [0,48M) over xb+WtDKVQ+WtUKV-head (all dead before build_k)
  u16* O  = ckvq;              // 32M over ckvq (dead after G23; flash runs after)

  // 1) prep: x cast + all weight transposes + pad zero (one launch)
  prep<<<8160, 256, 0, stream>>>(x, W_DKV, W_UK, W_UV, W_DQ, W_UQ, W_QR, W_KR, W_O,
                                 xb, WtDKVQ, WtUKV, WtO);

  // 2) G1+KR merged: ckvq = xb @ [W_DKV|W_DQ]^T ; kr = xb @ W_KR^T (n0==2048 block)
  gemm256<u16, 1><<<dim3(9, 32), 512, 0, stream>>>(xb, 2048, WtDKVQ, ckvq, 2048, 2048, kr, nullptr);

  // 3) G2+G3 merged: kc | Vt(transposed) | qcr in one N=7168 panel over contiguous UKV|UQR
  gemm256<u16, 2><<<dim3(28, 32), 512, 0, stream>>>(ckvq, 2048, WtUKV, kc, 2048, 1024, Vt, qcr);

  // 4) k rope+norm
  build_k<<<32768, 256, 0, stream>>>(kc, kr, kn);

  // 5) attention (fused Q rope+norm), 256 blocks, balanced q-tile pairs
  flash_attn<<<dim3(256), 512, 0, stream>>>(qcr, kn, Vt, s_qk, O);

  // 6) output projection -> fp32 d_out
  gemm256<float, 0><<<dim3(8, 32), 512, 0, stream>>>(O, 2048, WtO, (float*)d_out, 2048, 2048,
                                                     nullptr, nullptr);
}

// Round 5
// 587.482 us; speedup vs baseline: 2.1667x; 1.0606x over previous
//
#include <hip/hip_runtime.h>
#include <stdint.h>

typedef unsigned short u16;
typedef unsigned int u32;
typedef short bf16x8 __attribute__((ext_vector_type(8)));
typedef float f32x4 __attribute__((ext_vector_type(4)));
typedef u16 u16x4 __attribute__((ext_vector_type(4)));

#define DEV __device__ __forceinline__

DEV float bf2f(u16 u) { union { float f; u32 i; } x; x.i = ((u32)u) << 16; return x.f; }
DEV u16 f2bf(float f) {
  union { float f; u32 i; } x; x.f = f;
  u32 i = x.i;
  u32 r = (i + 0x7fffu + ((i >> 16) & 1u)) >> 16;  // RTNE
  return (u16)r;
}

// async global->LDS, 16B per lane. lds base must be wave-uniform; HW adds lane*16.
DEV void gl_lds16(const u16* g, u16* l) {
  __builtin_amdgcn_global_load_lds((const __attribute__((address_space(1))) u32*)g,
                                   (__attribute__((address_space(3))) u32*)l, 16, 0, 0);
}

// ---------------- prep: x cast + all weight transposes, ONE launch ----------------
__global__ __launch_bounds__(256) void prep(const float* __restrict__ x,
                                            const float* __restrict__ W_DKV,
                                            const float* __restrict__ W_UK,
                                            const float* __restrict__ W_UV,
                                            const float* __restrict__ W_DQ,
                                            const float* __restrict__ W_UQ,
                                            const float* __restrict__ W_QR,
                                            const float* __restrict__ W_KR,
                                            const float* __restrict__ W_O,
                                            u16* __restrict__ xb,
                                            u16* __restrict__ WtDKVQ,   // 2048 x 2048 (DKV|DQ)
                                            u16* __restrict__ WtUKV,    // 7168 x 1024 (UK|UV|UQ|QR)
                                            u16* __restrict__ WtKR,     // 64 x 2048
                                            u16* __restrict__ WtO) {
  __shared__ float tile[64][65];
  const int tid = threadIdx.x;
  int bid = blockIdx.x;

  if (bid < 4096) {   // cast x -> bf16, 4 float4 per thread
#pragma unroll
    for (int it = 0; it < 4; ++it) {
      int i = bid * 1024 + it * 256 + tid;
      float4 v = ((const float4*)x)[i];
      u16x4 o;
      o.x = f2bf(v.x); o.y = f2bf(v.y); o.z = f2bf(v.z); o.w = f2bf(v.w);
      ((u16x4*)xb)[i] = o;
    }
    return;
  }
  bid -= 4096;

  const float* W; u16* Wt; int K, N;
  if (bid < 512)        { W = W_DKV; Wt = WtDKVQ;                K = 2048; N = 1024; }
  else if (bid < 1024)  { W = W_DQ;  Wt = WtDKVQ + 1024 * 2048;  K = 2048; N = 1024; bid -= 512; }
  else if (bid < 1536)  { W = W_UK;  Wt = WtUKV;                 K = 1024; N = 2048; bid -= 1024; }
  else if (bid < 2048)  { W = W_UV;  Wt = WtUKV + 2048 * 1024;   K = 1024; N = 2048; bid -= 1536; }
  else if (bid < 2560)  { W = W_UQ;  Wt = WtUKV + 4096 * 1024;   K = 1024; N = 2048; bid -= 2048; }
  else if (bid < 2816)  { W = W_QR;  Wt = WtUKV + 6144 * 1024;   K = 1024; N = 1024; bid -= 2560; }
  else if (bid < 2848)  { W = W_KR;  Wt = WtKR;                  K = 2048; N = 64;   bid -= 2816; }
  else                  { W = W_O;   Wt = WtO;                   K = 2048; N = 2048; bid -= 2848; }

  const int gx = N >> 6;
  const int n0 = (bid % gx) * 64;
  const int k0 = (bid / gx) * 64;
#pragma unroll
  for (int i = 0; i < 16; ++i) {
    int idx = tid + i * 256;
    int r = idx >> 6, c = idx & 63;             // r: k-off, c: n-off
    tile[r][c] = W[(size_t)(k0 + r) * N + n0 + c];
  }
  __syncthreads();
#pragma unroll
  for (int i = 0; i < 16; ++i) {
    int idx = tid + i * 256;
    int r = idx >> 6, c = idx & 63;             // r: n-off, c: k-off
    Wt[(size_t)(n0 + r) * K + k0 + c] = f2bf(tile[c][r]);
  }
}

DEV void ep_set(u16* E, int i, float v) { E[i] = f2bf(v); }
DEV void ep_set(float* E, int i, float v) { E[i] = v; }

// ---------------- GEMM 256x256 8-phase (T2+T3+T4+T5): C = A(MxK) * Bt(NxK)^T ----------------
// KIND 0: plain C, 2-D grid.  KIND 2 (G2+G3 merged + KR tail): 1-D grid of 928.
//   main 896: n0<2048 -> C=kc; [2048,4096) -> X1=Vt TRANSPOSED; >=4096 -> X2=qcr, A+1024.
//   tail 32 (last 4 slots of each XCD chunk): kr(8192x64) = A2(xb) @ B2(WtKR)^T -> C2.
// Block mapping: XCD-chunked + 4-m-inner (concurrent set = 4m x 8n -> ~6MB, fits L2).
// Counted vmcnt(4) once per K-tile, raw s_barrier, read-side XOR swizzle with
// pre-swizzled global source (both-sides rule), setprio around MFMA.
template <typename OT, int KIND>
__global__ __launch_bounds__(512, 2) void gemm256(const u16* __restrict__ A, int lda,
                                                  const u16* __restrict__ Bt,
                                                  OT* __restrict__ C, int ldc, int K,
                                                  u16* __restrict__ X1, u16* __restrict__ X2,
                                                  const u16* __restrict__ A2,
                                                  const u16* __restrict__ B2,
                                                  u16* __restrict__ C2) {
  __shared__ u16 smem[65536];   // 128KB: buf[t&1]{ A[2][256][32] | B[2][256][32] }
  const int tid = threadIdx.x;
  const int lane = tid & 63;
  const int w = tid >> 6;       // 0..7
  const int wm = w >> 2;        // 0..1 (M)
  const int wn = w & 3;         // 0..3 (N)
  const int quad = lane >> 4;
  const int l15 = lane & 15;
  const int cs = quad ^ ((l15 >> 1) & 3);   // swizzled k-chunk for frag reads

  int m0, n0;
  if constexpr (KIND == 2) {
    const int lin2 = blockIdx.x;       // 0..927
    const int xcd2 = lin2 & 7;
    const int pos = lin2 >> 3;         // 0..115
    if (pos >= 112) {
      // ---- KR tail blocks: kr = xb @ WtKR^T (M=8192,N=64,K=2048), 4 per XCD ----
      const int idx = xcd2 * 4 + (pos - 112);   // m-block 0..31
      u16* Ab2 = smem;                           // [2][256*64] u16 (64KB)
      u16* Bb2 = smem + 32768;                   // [2][64*64] u16 (16KB)
      const u16* Ag2 = A2 + (size_t)(idx * 256) * 2048;
      auto stg = [&](int t2, int bufi) {
        u16* Ad = Ab2 + bufi * 16384;
        u16* Bd = Bb2 + bufi * 4096;
#pragma unroll
        for (int i = 0; i < 4; ++i) {
          int cb = i * 512 + w * 64;          // wave-uniform
          int c = cb + lane;
          int r = c >> 3, cp = (c & 7) ^ (r & 7);   // pre-swizzled source column
          gl_lds16(Ag2 + (size_t)r * 2048 + t2 * 64 + cp * 8, &Ad[cb * 8]);
        }
        {
          int cb = w * 64;
          int c = cb + lane;
          int r = c >> 3, cp = (c & 7) ^ (r & 7);
          gl_lds16(B2 + (size_t)r * 2048 + t2 * 64 + cp * 8, &Bd[cb * 8]);
        }
      };
      f32x4 acc2[2][4] = {};
      stg(0, 0);
      __syncthreads();
      for (int t2 = 0; t2 < 32; ++t2) {
        int cur = t2 & 1;
        if (t2 + 1 < 32) stg(t2 + 1, cur ^ 1);
        const u16* Ad = Ab2 + cur * 16384;
        const u16* Bd = Bb2 + cur * 4096;
#pragma unroll
        for (int kq = 0; kq < 2; ++kq) {
          bf16x8 bfr[4];
#pragma unroll
          for (int n = 0; n < 4; ++n)
            bfr[n] = *(const bf16x8*)&Bd[(n * 16 + l15) * 64 + ((kq * 4 + quad) ^ (l15 & 7)) * 8];
#pragma unroll
          for (int mt = 0; mt < 2; ++mt) {
            bf16x8 afr = *(const bf16x8*)&Ad[(w * 32 + mt * 16 + l15) * 64 + ((kq * 4 + quad) ^ (l15 & 7)) * 8];
#pragma unroll
            for (int n = 0; n < 4; ++n)
              acc2[mt][n] = __builtin_amdgcn_mfma_f32_16x16x32_bf16(afr, bfr[n], acc2[mt][n], 0, 0, 0);
          }
        }
        __syncthreads();
      }
#pragma unroll
      for (int mt = 0; mt < 2; ++mt)
#pragma unroll
        for (int n = 0; n < 4; ++n)
#pragma unroll
          for (int r = 0; r < 4; ++r)
            C2[(size_t)(idx * 256 + w * 32 + mt * 16 + quad * 4 + r) * 64 + n * 16 + l15] =
                f2bf(acc2[mt][n][r]);
      return;
    }
    // main mapping: c in [0,896), 4-m-inner (concurrent = 4m x 8n)
    const int c = xcd2 * 112 + pos;
    const int g4 = c >> 2;
    n0 = (g4 % 28) * 256;
    m0 = ((g4 / 28) * 4 + (c & 3)) * 256;
  } else {
    const int nwg = gridDim.x * gridDim.y;
    const int lin = blockIdx.y * gridDim.x + blockIdx.x;
    const int swz = (lin & 7) * (nwg >> 3) + (lin >> 3);
    const int g4 = swz >> 2;
    n0 = (g4 % gridDim.x) * 256;
    m0 = ((g4 / gridDim.x) * 4 + (swz & 3)) * 256;   // requires gridDim.y % 4 == 0
  }

  // staging per-thread geometry: thread covers row rloc, phys chunk tid&3;
  // pre-swizzled source column so linear LDS dest + swizzled read match.
  const int rloc = tid >> 2;                       // 0..127
  const int clog = (tid & 3) ^ ((tid >> 3) & 3);   // pre-swizzled source column
  const u16* Abase = A + ((KIND == 2 && n0 >= 4096) ? 1024 : 0);
  const size_t aoff0 = (size_t)rloc * lda + clog * 8;
  const size_t boff0 = (size_t)rloc * (size_t)K + clog * 8;
  const u16* Ag = Abase + (size_t)m0 * lda;
  const u16* Bg = Bt + (size_t)n0 * K;

  auto stageA = [&](int u, int ks2) {
    u16* dst = smem + (u & 1) * 32768 + ks2 * 8192 + w * 512;
    const u16* s0 = Ag + aoff0 + u * 64 + ks2 * 32;
    gl_lds16(s0, dst);
    gl_lds16(s0 + (size_t)128 * lda, dst + 4096);
  };
  auto stageB = [&](int u, int ks2) {
    u16* dst = smem + (u & 1) * 32768 + 16384 + ks2 * 8192 + w * 512;
    const u16* s0 = Bg + boff0 + u * 64 + ks2 * 32;
    gl_lds16(s0, dst);
    gl_lds16(s0 + (size_t)128 * (size_t)K, dst + 4096);
  };

  f32x4 acc[2][4][4] = {};   // [mq][mt][n], all indices compile-time
  const int nt = K >> 6;

  stageA(0, 0); stageB(0, 0); stageA(0, 1); stageB(0, 1);
  stageA(1, 0); stageB(1, 0);
  asm volatile("s_waitcnt vmcnt(4)" ::: "memory");
  __builtin_amdgcn_s_barrier();

  for (int t = 0; t < nt; ++t) {
    const u16* As_ = smem + (t & 1) * 32768;
    const u16* Bs_ = As_ + 16384;
#pragma unroll
    for (int p = 0; p < 4; ++p) {
      const int ks = p >> 1;
      const int mq = p & 1;
      const u16* Ab = As_ + ks * 8192;
      const u16* Bb = Bs_ + ks * 8192;
      bf16x8 af[4], bf[4];
#pragma unroll
      for (int mt = 0; mt < 4; ++mt)
        af[mt] = *(const bf16x8*)&Ab[(wm * 128 + mq * 64 + mt * 16 + l15) * 32 + cs * 8];
#pragma unroll
      for (int n = 0; n < 4; ++n)
        bf[n] = *(const bf16x8*)&Bb[(wn * 64 + n * 16 + l15) * 32 + cs * 8];
      if (p == 0)      { if (t + 1 < nt) stageA(t + 1, 1); }
      else if (p == 1) { if (t + 1 < nt) stageB(t + 1, 1); }
      else if (p == 2) { if (t + 2 < nt) stageA(t + 2, 0); }
      else             { if (t + 2 < nt) stageB(t + 2, 0); }
      __builtin_amdgcn_s_barrier();
      __builtin_amdgcn_s_setprio(1);
#pragma unroll
      for (int mt = 0; mt < 4; ++mt)
#pragma unroll
        for (int n = 0; n < 4; ++n)
          acc[mq][mt][n] = __builtin_amdgcn_mfma_f32_16x16x32_bf16(af[mt], bf[n], acc[mq][mt][n], 0, 0, 0);
      __builtin_amdgcn_s_setprio(0);
      if (p == 3) asm volatile("s_waitcnt vmcnt(4)" ::: "memory");
      __builtin_amdgcn_s_barrier();
    }
  }
  asm volatile("s_waitcnt vmcnt(0)" ::: "memory");
  __builtin_amdgcn_s_barrier();

  if constexpr (KIND == 2) {
    if (n0 >= 2048 && n0 < 4096) {
      // VMODE: write this quadrant transposed into Vt (b,h,dv,L).
      u16* Ewt = smem + w * 2560;        // 64 * 40 u16 = 5120B per wave
      const int dvb = (n0 - 2048) + wn * 64;
      const int hh = dvb >> 7;
      const int dv0 = dvb & 127;         // 0 or 64
#pragma unroll
      for (int mq = 0; mq < 2; ++mq)
#pragma unroll
        for (int mh = 0; mh < 2; ++mh) {
#pragma unroll
          for (int mi = 0; mi < 2; ++mi)
#pragma unroll
            for (int n = 0; n < 4; ++n)
#pragma unroll
              for (int r = 0; r < 4; ++r)
                Ewt[(n * 16 + l15) * 40 + mi * 16 + quad * 4 + r] = f2bf(acc[mq][mh * 2 + mi][n][r]);
          asm volatile("s_waitcnt lgkmcnt(0)" ::: "memory");
          const int mbase = m0 + wm * 128 + mq * 64 + mh * 32;
          const int b_ = mbase >> 11, l_ = mbase & 2047;
          u16* dstp = X1 + ((size_t)((b_ * 16 + hh) * 128 + dv0 + lane)) * 2048 + l_;
          const u16* srcp = &Ewt[lane * 40];
#pragma unroll
          for (int k2 = 0; k2 < 4; ++k2)
            *(uint4*)&dstp[k2 * 8] = *(const uint4*)&srcp[k2 * 8];
          asm volatile("s_waitcnt lgkmcnt(0)" ::: "memory");
        }
      return;
    }
  }

  // normal epilogue: wide stores via per-wave LDS region (16 rows x 64 cols per pass)
  OT* Cc = C; int ldcc = ldc, col0 = n0;
  if constexpr (KIND == 2) {
    if (n0 >= 4096) { Cc = (OT*)X2; ldcc = 3072; col0 = n0 - 4096; }
  }
  OT* Ew = ((OT*)smem) + w * 1024;
#pragma unroll
  for (int mq = 0; mq < 2; ++mq) {
#pragma unroll
    for (int mt = 0; mt < 4; ++mt) {
#pragma unroll
      for (int n = 0; n < 4; ++n)
#pragma unroll
        for (int r = 0; r < 4; ++r)
          ep_set(Ew, (quad * 4 + r) * 64 + n * 16 + l15, acc[mq][mt][n][r]);
      asm volatile("s_waitcnt lgkmcnt(0)" ::: "memory");
#pragma unroll
      for (int it2 = 0; it2 < 4; ++it2) {
        int row_i = it2 * 4 + quad;
        size_t off = (size_t)(m0 + wm * 128 + mq * 64 + mt * 16 + row_i) * ldcc + col0 + wn * 64 + l15 * 4;
        if constexpr (sizeof(OT) == 2) {
          *(u16x4*)&Cc[off] = *(const u16x4*)&Ew[row_i * 64 + l15 * 4];
        } else {
          *(float4*)&Cc[off] = *(const float4*)&Ew[row_i * 64 + l15 * 4];
        }
      }
      asm volatile("s_waitcnt lgkmcnt(0)" ::: "memory");  // Ew reads done before rewrite
    }
  }
}

// ---------------- build k: rope + concat + L2-normalize, one wave per (token, head) ----------------
__global__ __launch_bounds__(256) void build_k(const u16* __restrict__ kc,   // (B*L, 2048)
                                               const u16* __restrict__ krr,  // (B*L, 64)
                                               u16* __restrict__ kn) {
  const int wid = blockIdx.x * 4 + (threadIdx.x >> 6);
  const int lane = threadIdx.x & 63;
  const int token = wid >> 4;
  const int h = wid & 15;
  const int b = token >> 11;
  const int l = token & 2047;
  float v0 = bf2f(kc[(size_t)token * 2048 + h * 128 + lane]);
  float v1 = bf2f(kc[(size_t)token * 2048 + h * 128 + 64 + lane]);
  int j = lane & 31;
  float freq = __expf((float)j * -0.28782313662425574f);   // 10000^(-j/32)
  float ang = (float)l * freq;
  float cs = __cosf(ang), sn = __sinf(ang);
  float xr = bf2f(krr[(size_t)token * 64 + lane]);
  float xo = bf2f(krr[(size_t)token * 64 + (lane ^ 32)]);
  float v2 = (lane < 32) ? (xr * cs - xo * sn) : (xr * cs + xo * sn);
  float ss = v0 * v0 + v1 * v1 + v2 * v2;
#pragma unroll
  for (int off = 1; off < 64; off <<= 1) ss += __shfl_xor(ss, off, 64);
  float scale = 1.0f / fmaxf(sqrtf(ss), 1e-12f);
  u16* out = kn + (((size_t)(b * 16 + h) * 2048) + l) * 192;
  out[lane] = f2bf(v0 * scale);
  out[64 + lane] = f2bf(v1 * scale);
  out[128 + lane] = f2bf(v2 * scale);
}

// ---------------- flash attention (causal), 512 thr, balanced pairing, fused Q-build ----------------
__global__ __launch_bounds__(512, 2) void flash_attn(const u16* __restrict__ qcr, // (B*L, 3072): qc|qr
                                                     const u16* __restrict__ Kn,  // (B,H,L,192)
                                                     const u16* __restrict__ Vt,  // (B,H,128,L)
                                                     const float* __restrict__ s_qk,
                                                     u16* __restrict__ O) {       // (B,L,2048)
  constexpr int L = 2048, DQK = 192, KVB = 64;
  constexpr int DV = 128; (void)DV;
  constexpr int PSTR = 72;
  __shared__ u16 smem[59392];          // Ks[2][64*192] | Vs[2][128*64] | Ps[8*32*72] = 118784 B
  u16* KsBuf = smem;                   // 2 x 12288 u16
  u16* VsBuf = smem + 24576;           // 2 x 8192 u16
  u16* Ps    = smem + 40960;           // 18432 u16
  const int tid = threadIdx.x;
  const int lane = tid & 63;
  const int w = tid >> 6;       // 0..7, q-row group (32 rows each)
  const int quad = lane >> 4;
  const int l15 = lane & 15;
  const int lin = blockIdx.x;
  const int xcd = lin & 7;
  const int g = lin >> 3;         // 0..31
  const int bh = ((g >> 2) << 3) | xcd;
  const int pairIdx = g & 3;      // qtA = 7-pairIdx, qtB = pairIdx -> 36 tiles each
  const int b = bh >> 4, h = bh & 15;
  const float SMAX = s_qk[0];     // upper bound on every score (unit q,k; q pre-scaled)

  const u16* Kg = Kn + (size_t)bh * L * DQK;
  const u16* Vg = Vt + (size_t)bh * 128 * L;

  // stage address precompute (constant across kt)
  int koffs[3], kdsts[3], voffs[2], vdsts[2];
#pragma unroll
  for (int it = 0; it < 3; ++it) {
    int p = it * 512 + w * 64 + lane;
    int r = p / 24, cp = p % 24;
    koffs[it] = r * DQK + (cp ^ (r & 7)) * 8;
    kdsts[it] = (it * 512 + w * 64) * 8;
  }
#pragma unroll
  for (int it = 0; it < 2; ++it) {
    int q = (it + 3) * 512 + w * 64 + lane - 1536;
    int dv = q >> 3, cp = q & 7;
    voffs[it] = dv * L + (cp ^ (dv & 7)) * 8;
    vdsts[it] = ((it + 3) * 512 + w * 64 - 1536) * 8;
  }

  auto stage = [&](int kt2, int bufi) {
    u16* KsB = KsBuf + bufi * 12288;
    u16* VsB = VsBuf + bufi * 8192;
    const u16* Kt = Kg + (size_t)(kt2 * KVB) * DQK;
    const u16* Vtb = Vg + kt2 * KVB;
#pragma unroll
    for (int it = 0; it < 3; ++it) gl_lds16(Kt + koffs[it], &KsB[kdsts[it]]);
#pragma unroll
    for (int it = 0; it < 2; ++it) gl_lds16(Vtb + voffs[it], &VsB[vdsts[it]]);
  };

  bf16x8 ones;
#pragma unroll
  for (int j = 0; j < 8; ++j) ones[j] = (short)0x3F80;   // bf16 1.0

  for (int qp = 0; qp < 2; ++qp) {
    const int qt = (qp == 0) ? (7 - pairIdx) : pairIdx;

    // ---- fused Q-build: load raw qc|qr, rope kd4/5, L2-normalize, scale by s_qk ----
    bf16x8 qf[2][6];
#pragma unroll
    for (int mt = 0; mt < 2; ++mt) {
      const int row = qt * 256 + w * 32 + mt * 16 + l15;
      const u16* qr_ = qcr + (size_t)(b * 2048 + row) * 3072;
#pragma unroll
      for (int kd = 0; kd < 4; ++kd)
        qf[mt][kd] = *(const bf16x8*)&qr_[h * 128 + kd * 32 + quad * 8];
      bf16x8 a4 = *(const bf16x8*)&qr_[2048 + h * 64 + quad * 8];
      bf16x8 a5 = *(const bf16x8*)&qr_[2048 + h * 64 + 32 + quad * 8];
      float v4[8], v5[8];
      float ss = 0.f;
#pragma unroll
      for (int e = 0; e < 8; ++e) {
        int j = quad * 8 + e;
        float fr = __expf((float)j * -0.28782313662425574f);
        float ang = (float)row * fr;
        float cs2 = __cosf(ang), sn2 = __sinf(ang);
        float x4 = bf2f((u16)a4[e]), x5 = bf2f((u16)a5[e]);
        v4[e] = x4 * cs2 - x5 * sn2;
        v5[e] = x5 * cs2 + x4 * sn2;
        ss += v4[e] * v4[e] + v5[e] * v5[e];
      }
#pragma unroll
      for (int kd = 0; kd < 4; ++kd)
#pragma unroll
        for (int e = 0; e < 8; ++e) { float xv = bf2f((u16)qf[mt][kd][e]); ss += xv * xv; }
      ss += __shfl_xor(ss, 16, 64);
      ss += __shfl_xor(ss, 32, 64);
      float scale = SMAX / fmaxf(sqrtf(ss), 1e-12f);
#pragma unroll
      for (int kd = 0; kd < 4; ++kd) {
        bf16x8 t = qf[mt][kd];
#pragma unroll
        for (int e = 0; e < 8; ++e) t[e] = (short)f2bf(bf2f((u16)t[e]) * scale);
        qf[mt][kd] = t;
      }
      bf16x8 t4, t5;
#pragma unroll
      for (int e = 0; e < 8; ++e) { t4[e] = (short)f2bf(v4[e] * scale); t5[e] = (short)f2bf(v5[e] * scale); }
      qf[mt][4] = t4; qf[mt][5] = t5;
    }

    f32x4 oacc[2][8] = {};
    f32x4 accL[2] = {};           // running row-sum of P via ones-MFMA

    const int nkv = 4 * (qt + 1);   // 64-key tiles
    stage(0, 0);
    __syncthreads();

    for (int kt = 0; kt < nkv; ++kt) {
      const int cur = kt & 1;
      if (kt + 1 < nkv) stage(kt + 1, cur ^ 1);   // prefetch overlaps compute
      const u16* KsC = KsBuf + cur * 12288;
      const u16* VsC = VsBuf + cur * 8192;

      f32x4 s[2][4] = {};
      __builtin_amdgcn_s_setprio(1);
#pragma unroll
      for (int kd = 0; kd < 6; ++kd) {
#pragma unroll
        for (int nt = 0; nt < 4; ++nt) {
          int row = nt * 16 + l15;
          int cp = (kd * 4 + quad) ^ (l15 & 7);
          bf16x8 bb = *(const bf16x8*)&KsC[row * DQK + cp * 8];
#pragma unroll
          for (int mt = 0; mt < 2; ++mt)
            s[mt][nt] = __builtin_amdgcn_mfma_f32_16x16x32_bf16(qf[mt][kd], bb, s[mt][nt], 0, 0, 0);
        }
      }
      __builtin_amdgcn_s_setprio(0);

      const int kcol0 = kt * KVB + l15;
      u16* Pw = &Ps[w * 32 * PSTR];
#pragma unroll
      for (int mt = 0; mt < 2; ++mt) {
        const int qrow_base = qt * 256 + w * 32 + mt * 16 + quad * 4;
#pragma unroll
        for (int r = 0; r < 4; ++r)
#pragma unroll
          for (int nt = 0; nt < 4; ++nt) {
            float p = (kcol0 + nt * 16 > qrow_base + r) ? 0.f : __expf(s[mt][nt][r] - SMAX);
            Pw[(mt * 16 + quad * 4 + r) * PSTR + nt * 16 + l15] = f2bf(p);
          }
      }
      asm volatile("s_waitcnt lgkmcnt(0)" ::: "memory");

      __builtin_amdgcn_s_setprio(1);
      bf16x8 pf[2][2];
#pragma unroll
      for (int mt = 0; mt < 2; ++mt)
#pragma unroll
        for (int kc2 = 0; kc2 < 2; ++kc2) {
          pf[mt][kc2] = *(const bf16x8*)&Pw[(mt * 16 + l15) * PSTR + kc2 * 32 + quad * 8];
          accL[mt] = __builtin_amdgcn_mfma_f32_16x16x32_bf16(pf[mt][kc2], ones, accL[mt], 0, 0, 0);
        }
#pragma unroll
      for (int nt2 = 0; nt2 < 8; ++nt2) {
        const int dv = nt2 * 16 + l15;
#pragma unroll
        for (int kc2 = 0; kc2 < 2; ++kc2) {
          int lc = (kc2 * 4 + quad) ^ (l15 & 7);   // dv&7 == l15&7
          bf16x8 vv = *(const bf16x8*)&VsC[dv * KVB + lc * 8];
#pragma unroll
          for (int mt = 0; mt < 2; ++mt)
            oacc[mt][nt2] = __builtin_amdgcn_mfma_f32_16x16x32_bf16(pf[mt][kc2], vv, oacc[mt][nt2], 0, 0, 0);
        }
      }
      __builtin_amdgcn_s_setprio(0);
      __syncthreads();  // drains prefetch (vmcnt) + frees cur buffer
    }

    float rinv[2][4];
#pragma unroll
    for (int mt = 0; mt < 2; ++mt)
#pragma unroll
      for (int r = 0; r < 4; ++r) rinv[mt][r] = 1.0f / accL[mt][r];
    u16* Ew = smem + w * 2048;
#pragma unroll
    for (int mt = 0; mt < 2; ++mt) {
#pragma unroll
      for (int nt2 = 0; nt2 < 8; ++nt2)
#pragma unroll
        for (int r = 0; r < 4; ++r)
          Ew[(quad * 4 + r) * 128 + nt2 * 16 + l15] = f2bf(oacc[mt][nt2][r] * rinv[mt][r]);
      asm volatile("s_waitcnt lgkmcnt(0)" ::: "memory");
#pragma unroll
      for (int it2 = 0; it2 < 4; ++it2) {
        int row_i = it2 * 4 + quad;
        int lg = qt * 256 + w * 32 + mt * 16 + row_i;
        uint4 v = *(const uint4*)&Ew[row_i * 128 + l15 * 8];
        *(uint4*)&O[((size_t)b * L + lg) * 2048 + h * 128 + l15 * 8] = v;
      }
      asm volatile("s_waitcnt lgkmcnt(0)" ::: "memory");
    }
    __syncthreads();   // protect Ew region before next pass's stage(0,0)
  }
}

// ---------------- launcher ----------------
extern "C" void kernel_launch(void* const* d_in, const int* in_sizes, int n_in,
                              void* d_out, int out_size, void* d_ws, size_t ws_size,
                              hipStream_t stream) {
  const float* x     = (const float*)d_in[0];
  const float* W_DKV = (const float*)d_in[1];
  const float* W_UK  = (const float*)d_in[2];
  const float* W_UV  = (const float*)d_in[3];
  const float* W_DQ  = (const float*)d_in[4];
  const float* W_UQ  = (const float*)d_in[5];
  const float* W_QR  = (const float*)d_in[6];
  const float* W_KR  = (const float*)d_in[7];
  const float* W_O   = (const float*)d_in[8];
  const float* s_qk  = (const float*)d_in[9];

  char* base = (char*)d_ws;
  // static layout (bytes) — high-water ~208.3 MiB:
  u16* xb     = (u16*)(base);                        // [0, 32M)    live to G23 (KR tail reads it)
  u16* WtDKVQ = (u16*)(base + (size_t)33554432);     // 2048x2048, dead after G1
  u16* WtUKV  = (u16*)(base + (size_t)42991616);     // 7168x1024, dead after G23
  u16* WtO    = (u16*)(base + (size_t)57671680);     // live to end
  u16* ckvq   = (u16*)(base + (size_t)66060288);     // written G1, read G23, dead after
  u16* kc     = (u16*)(base + (size_t)99614720);     // written G23, read build_k
  u16* Vt     = (u16*)(base + (size_t)133169152);    // written G23 (VMODE), read flash
  u16* qcr    = (u16*)(base + (size_t)166723584);    // written G23, read flash (fused Q)
  u16* kr     = (u16*)(base + (size_t)217055232);    // written G23 (KR tail), read build_k
  u16* WtKR   = (u16*)(base + (size_t)218103808);    // 64x2048, read G23 (KR tail)
  // aliases:
  u16* kn = (u16*)(base);      // 50.33MB over xb+WtDKVQ+WtUKV-head (all dead before build_k)
  u16* O  = ckvq;              // 32M over ckvq (dead after G23; flash runs after)

  // 1) prep: x cast + all weight transposes (one launch)
  prep<<<7968, 256, 0, stream>>>(x, W_DKV, W_UK, W_UV, W_DQ, W_UQ, W_QR, W_KR, W_O,
                                 xb, WtDKVQ, WtUKV, WtKR, WtO);

  // 2) G1: ckvq = xb @ [W_DKV|W_DQ]^T — exactly 256 blocks (1 round)
  gemm256<u16, 0><<<dim3(8, 32), 512, 0, stream>>>(xb, 2048, WtDKVQ, ckvq, 2048, 2048,
                                                   nullptr, nullptr, nullptr, nullptr, nullptr);

  // 3) G23: kc | Vt(transposed) | qcr (896 blocks) + KR tail (32 blocks, fills idle CUs)
  gemm256<u16, 2><<<dim3(928), 512, 0, stream>>>(ckvq, 2048, WtUKV, kc, 2048, 1024,
                                                 Vt, qcr, xb, WtKR, kr);

  // 4) k rope+norm
  build_k<<<32768, 256, 0, stream>>>(kc, kr, kn);

  // 5) attention (fused Q rope+norm), 256 blocks, balanced q-tile pairs
  flash_attn<<<dim3(256), 512, 0, stream>>>(qcr, kn, Vt, s_qk, O);

  // 6) output projection -> fp32 d_out (exactly 256 blocks)
  gemm256<float, 0><<<dim3(8, 32), 512, 0, stream>>>(O, 2048, WtO, (float*)d_out, 2048, 2048,
                                                     nullptr, nullptr, nullptr, nullptr, nullptr);
}